// Round 12
// baseline (169.634 us; speedup 1.0000x reference)
//
#include <hip/hip_runtime.h>

// ---- ws layout (float offsets) ----
// G: per-pair conv1 tables [1024][4][48] (F_s + F_t)           = 196608 floats
// H: per-edge conv1 tables [256][4][48]  (F_u + F_v + b1)      = 49152 floats
constexpr int G_OFF = 0;
constexpr int H_OFF = 196608;
constexpr int PREDS_OFF = H_OFF + 49152;        // 245760
constexpr int RBCP_OFF = PREDS_OFF + 262144;    // 507904: rbc_part[64][32]
constexpr int CNT_OFF = RBCP_OFF + 2048;        // 509952 (legacy pad)
constexpr int W1P_OFF = CNT_OFF + 16;           // 509968: fc1 A-frags 4096 shorts
constexpr int W2P_OFF = W1P_OFF + 2048;         // 512016: fc2 A-frags 32768 shorts
constexpr int W3P_OFF = W2P_OFF + 16384;        // 528400: fc3 A-frags 32768 shorts
constexpr int BASE_FLOATS = 544784;
// C1: conv3 output staging [4096 blocks][2][64][8] shorts = 4 Mi shorts = 2 Mi floats
constexpr int C1_OFF = BASE_FLOATS;
constexpr size_t SPLIT_WS_FLOATS = (size_t)BASE_FLOATS + 4096 * 512;  // 512 f/block

typedef __attribute__((ext_vector_type(8))) short short8;
typedef __attribute__((ext_vector_type(4))) short short4v;
typedef __attribute__((ext_vector_type(4))) float f32x4;
typedef __attribute__((ext_vector_type(2))) unsigned int uint2v;

__device__ __forceinline__ unsigned short f2bf(float x) {  // RNE bf16 (prep only)
    unsigned u = __float_as_uint(x);
    u += 0x7FFF + ((u >> 16) & 1);
    return (unsigned short)(u >> 16);
}

// One-instruction packed f32->bf16 pair (low = a, high = b).
__device__ __forceinline__ unsigned cvt_pk_bf16(float a, float b) {
    unsigned r;
    asm("v_cvt_pk_bf16_f32 %0, %1, %2" : "=v"(r) : "v"(a), "v"(b));
    return r;
}

// quad_perm DPP: lane -> lane^m within each 4-lane quad (VALU, no LDS pipe).
template <int CTRL>
__device__ __forceinline__ float qp(float x) {
    return __int_as_float(__builtin_amdgcn_update_dpp(
        0, __float_as_int(x), CTRL, 0xF, 0xF, true));
}

// ---------------- Kernel 0: all preprocessing ----------------
__global__ void prep_all(const float* __restrict__ emb, const int* __restrict__ edges,
                         const float* __restrict__ w1, const float* __restrict__ b1,
                         const float* __restrict__ fc1_w, const float* __restrict__ fc2_w,
                         const float* __restrict__ fc3_w,
                         float* __restrict__ G, float* __restrict__ H,
                         unsigned short* __restrict__ W1p,
                         unsigned short* __restrict__ W2p, unsigned short* __restrict__ W3p,
                         float* __restrict__ rbcp_zero) {
    int b = blockIdx.x;
    if (b < 768) {  // G[p][o][i] = conv1 contribution of (s as c0) + (t as c1)
        int idx = b * 256 + threadIdx.x;  // 196608
        int i = idx % 48;
        int o = (idx / 48) & 3;
        int p = idx / 192;
        int s = p >> 5, t = p & 31;
        float acc = 0.f;
        if (i < 46) {
#pragma unroll
            for (int k = 0; k < 3; k++)
                acc += w1[(o * 4 + 0) * 3 + k] * emb[s * 96 + 2 * i + k] +
                       w1[(o * 4 + 1) * 3 + k] * emb[t * 96 + 2 * i + k];
        }
        G[idx] = acc;
        return;
    }
    if (b < 960) {  // H[e][o][i] = conv1 contribution of (u as c2) + (v as c3) + b1[o]
        int idx = (b - 768) * 256 + threadIdx.x;  // 49152
        int i = idx % 48;
        int o = (idx / 48) & 3;
        int e = idx / 192;
        int u = edges[2 * e], v = edges[2 * e + 1];
        float acc = 0.f;
        if (i < 46) {
            acc = b1[o];
#pragma unroll
            for (int k = 0; k < 3; k++)
                acc += w1[(o * 4 + 2) * 3 + k] * emb[u * 96 + 2 * i + k] +
                       w1[(o * 4 + 3) * 3 + k] * emb[v * 96 + 2 * i + k];
        }
        H[idx] = acc;
        return;
    }
    if (b < 976) {  // fc1 A-layout, K padded 16->32, single bf16
        int t = (b - 960) * 256 + threadIdx.x;  // 4096
        int j = t & 7, lane = (t >> 3) & 63, mt = t >> 9;
        int k = (lane >> 4) * 8 + j, n = mt * 16 + (lane & 15);
        float w = (k < 16) ? fc1_w[k * 128 + n] : 0.f;
        W1p[t] = f2bf(w);
        return;
    }
    if (b < 1104) {  // fc2 A-layout [16mt][4ks], single bf16
        int t = (b - 976) * 256 + threadIdx.x;  // 32768
        int j = t & 7, lane = (t >> 3) & 63, ks = (t >> 9) & 3, mt = t >> 11;
        int k = ks * 32 + (lane >> 4) * 8 + j, n = mt * 16 + (lane & 15);
        W2p[t] = f2bf(fc2_w[k * 256 + n]);
        return;
    }
    if (b < 1232) {  // fc3 A-layout [8mt][8ks], single bf16
        int t = (b - 1104) * 256 + threadIdx.x;  // 32768
        int j = t & 7, lane = (t >> 3) & 63, ks = (t >> 9) & 7, mt = t >> 12;
        int k = ks * 32 + (lane >> 4) * 8 + j, n = mt * 16 + (lane & 15);
        W3p[t] = f2bf(fc3_w[k * 128 + n]);
        return;
    }
    for (int k = threadIdx.x; k < 2064; k += 256) rbcp_zero[k] = 0.f;
}

// ====== Shared conv body (conv1 G+H -> conv2 DPP -> conv3 -> packed bf16x4) ======
__device__ __forceinline__ uint2v conv_body(
        const float* __restrict__ G, const float* __restrict__ H,
        const float* __restrict__ w2, const float* __restrict__ b2,
        const float* __restrict__ w3, const float* __restrict__ b3,
        int p, int e, int o) {
    float h1[23];
    {
        const f32x4* Gp = (const f32x4*)(G + (p * 4 + o) * 48);
        const f32x4* Hp = (const f32x4*)(H + (e * 4 + o) * 48);
        float pre[46];
#pragma unroll
        for (int q = 0; q < 12; q++) {
            f32x4 x = Gp[q] + Hp[q];
#pragma unroll
            for (int z = 0; z < 4; z++) {
                int i = 4 * q + z;
                if (i < 46) pre[i] = x[z];
            }
        }
#pragma unroll
        for (int j = 0; j < 23; j++) h1[j] = fmaxf(fmaxf(pre[2 * j], pre[2 * j + 1]), 0.f);
    }
    float h2[10];
    {
        float wm[4][3];  // wm[m][k] = w2[o][o^m][k]
#pragma unroll
        for (int m = 0; m < 4; m++)
#pragma unroll
            for (int k = 0; k < 3; k++) wm[m][k] = w2[o * 12 + (o ^ m) * 3 + k];
        const float bb = b2[o];
        float win[4][3];
#pragma unroll
        for (int j = 0; j < 2; j++) {
            float x = h1[j];
            win[0][j] = x;
            win[1][j] = qp<0xB1>(x);
            win[2][j] = qp<0x4E>(x);
            win[3][j] = qp<0x1B>(x);
        }
        float pre[20];
#pragma unroll
        for (int i = 0; i < 20; i++) {
            float x = h1[i + 2];
            win[0][(i + 2) % 3] = x;
            win[1][(i + 2) % 3] = qp<0xB1>(x);
            win[2][(i + 2) % 3] = qp<0x4E>(x);
            win[3][(i + 2) % 3] = qp<0x1B>(x);
            float acc = bb;
#pragma unroll
            for (int m = 0; m < 4; m++)
#pragma unroll
                for (int k = 0; k < 3; k++)
                    acc = fmaf(wm[m][k], win[m][(i + k) % 3], acc);
            pre[i] = acc;
        }
#pragma unroll
        for (int j = 0; j < 10; j++) h2[j] = fmaxf(fmaxf(pre[2 * j], pre[2 * j + 1]), 0.f);
    }
    {
        float wm[4][3];
#pragma unroll
        for (int m = 0; m < 4; m++)
#pragma unroll
            for (int k = 0; k < 3; k++) wm[m][k] = w3[o * 12 + (o ^ m) * 3 + k];
        const float bb = b3[o];
        float win[4][3];
#pragma unroll
        for (int j = 0; j < 2; j++) {
            float x = h2[j];
            win[0][j] = x;
            win[1][j] = qp<0xB1>(x);
            win[2][j] = qp<0x4E>(x);
            win[3][j] = qp<0x1B>(x);
        }
        float pre[8];
#pragma unroll
        for (int i = 0; i < 8; i++) {
            float x = h2[i + 2];
            win[0][(i + 2) % 3] = x;
            win[1][(i + 2) % 3] = qp<0xB1>(x);
            win[2][(i + 2) % 3] = qp<0x4E>(x);
            win[3][(i + 2) % 3] = qp<0x1B>(x);
            float acc = bb;
#pragma unroll
            for (int m = 0; m < 4; m++)
#pragma unroll
                for (int k = 0; k < 3; k++)
                    acc = fmaf(wm[m][k], win[m][(i + k) % 3], acc);
            pre[i] = acc;
        }
        float v0 = fmaxf(fmaxf(pre[0], pre[1]), 0.f);
        float v1 = fmaxf(fmaxf(pre[2], pre[3]), 0.f);
        float v2 = fmaxf(fmaxf(pre[4], pre[5]), 0.f);
        float v3 = fmaxf(fmaxf(pre[6], pre[7]), 0.f);
        uint2v d;
        d.x = cvt_pk_bf16(v0, v1);
        d.y = cvt_pk_bf16(v2, v3);
        return d;
    }
}

// ---------------- Kernel 1a (split path): conv only. No LDS, no barriers, no MFMA.
// launch_bounds(256, 8): VGPR capped at 64 (conv body already compiles to 64) ->
// 8 waves/SIMD, 2x the fused kernel's residency.
__global__ __launch_bounds__(256, 8)
void conv_kernel(const float* __restrict__ G, const float* __restrict__ H,
                 const float* __restrict__ w2, const float* __restrict__ b2,
                 const float* __restrict__ w3, const float* __restrict__ b3,
                 unsigned short* __restrict__ C1) {
    const int bid = (blockIdx.x & 7) * 512 + (blockIdx.x >> 3);  // XCD swizzle
    const int p = bid >> 2;
    const int e0 = (bid & 3) * 64;
    const int s = p >> 5, t = p & 31;
    if (s == t) return;
    const int tid = threadIdx.x;
    const int gsample = tid >> 2, o = tid & 3;
    uint2v d = conv_body(G, H, w2, b2, w3, b3, p, e0 + gsample, o);
    unsigned short* C1b = C1 + (size_t)bid * 1024;
    *(uint2v*)(C1b + (((o >> 1) * 64 + gsample) * 8) + (o & 1) * 4) = d;
}

// ---------------- Kernel 1b (split path): fc1..fc4. B-frag for fc1 from global C1.
__global__ __launch_bounds__(256, 4)
void fc_kernel(const unsigned short* __restrict__ C1,
               const float* __restrict__ fc1_b, const float* __restrict__ fc2_b,
               const float* __restrict__ fc3_b,
               const float* __restrict__ fc4_w, const float* __restrict__ fc4_b,
               const unsigned short* __restrict__ W1p, const unsigned short* __restrict__ W2p,
               const unsigned short* __restrict__ W3p,
               float* __restrict__ preds) {
    __shared__ __align__(16) float smem[8448];
    unsigned short* X3f = (unsigned short*)smem;
    unsigned short* X2 = (unsigned short*)(smem + 4096);
    float* part = smem + 8192;

    const int tid = threadIdx.x;
    const int bid = (blockIdx.x & 7) * 512 + (blockIdx.x >> 3);  // XCD swizzle
    const int p = bid >> 2;
    const int e0 = (bid & 3) * 64;
    const int s = p >> 5, t = p & 31;
    if (s == t) return;

    const int lane = tid & 63, wave = tid >> 6;
    const int mrow = lane & 15, quad = lane >> 4;

    // ---- fc1 MFMA: A=W1p, B from C1 (quad>=2 lanes hold the K-padding zeros) ----
    {
        const short8* W1v = (const short8*)W1p;
        short8 w1f[2];
#pragma unroll
        for (int mtl = 0; mtl < 2; mtl++)
            w1f[mtl] = W1v[(wave * 2 + mtl) * 64 + lane];
        const unsigned short* C1b = C1 + (size_t)bid * 1024;
        const short8 z8 = (short8){0, 0, 0, 0, 0, 0, 0, 0};
        short8 bnt[4];
#pragma unroll
        for (int nt = 0; nt < 4; nt++)
            bnt[nt] = (quad < 2) ? *(const short8*)(C1b + (quad * 64 + nt * 16 + mrow) * 8) : z8;
        f32x4 acc1[2][4];
#pragma unroll
        for (int a = 0; a < 2; a++)
#pragma unroll
            for (int b = 0; b < 4; b++) acc1[a][b] = (f32x4){0.f, 0.f, 0.f, 0.f};
#pragma unroll
        for (int mtl = 0; mtl < 2; mtl++) {
#pragma unroll
            for (int nt = 0; nt < 4; nt++)
                acc1[mtl][nt] = __builtin_amdgcn_mfma_f32_16x16x32_bf16(w1f[mtl], bnt[nt], acc1[mtl][nt], 0, 0, 0);
        }
#pragma unroll
        for (int mtl = 0; mtl < 2; mtl++) {
            const int mt = wave * 2 + mtl;
            const int n0 = mt * 16 + quad * 4;
            f32x4 b4 = *(const f32x4*)(fc1_b + n0);
#pragma unroll
            for (int nt = 0; nt < 4; nt++) {
                float x0 = fmaxf(acc1[mtl][nt][0] + b4[0], 0.f);
                float x1 = fmaxf(acc1[mtl][nt][1] + b4[1], 0.f);
                float x2 = fmaxf(acc1[mtl][nt][2] + b4[2], 0.f);
                float x3 = fmaxf(acc1[mtl][nt][3] + b4[3], 0.f);
                uint2v d;
                d.x = cvt_pk_bf16(x0, x1);
                d.y = cvt_pk_bf16(x2, x3);
                *(uint2v*)(X2 + ((n0 >> 3) * 64 + nt * 16 + mrow) * 8 + (n0 & 7)) = d;
            }
        }
    }
    __syncthreads();  // barrier 1: X2 ready
    const short8* W2v = (const short8*)W2p;
    const short8* W3v = (const short8*)W3p;
    f32x4 acc2[4][4];
#pragma unroll
    for (int a = 0; a < 4; a++)
#pragma unroll
        for (int b = 0; b < 4; b++) acc2[a][b] = (f32x4){0.f, 0.f, 0.f, 0.f};
#pragma unroll
    for (int ks = 0; ks < 4; ks++) {
        short8 bfr[4];
#pragma unroll
        for (int nt = 0; nt < 4; nt++)
            bfr[nt] = *(const short8*)(X2 + ((ks * 4 + quad) * 64 + nt * 16 + mrow) * 8);
#pragma unroll
        for (int q = 0; q < 4; q++) {
            const int mt = q * 4 + wave;
            short8 ah = W2v[(mt * 4 + ks) * 64 + lane];
#pragma unroll
            for (int nt = 0; nt < 4; nt++)
                acc2[q][nt] = __builtin_amdgcn_mfma_f32_16x16x32_bf16(ah, bfr[nt], acc2[q][nt], 0, 0, 0);
        }
    }
    __syncthreads();  // barrier 2: X2 reads done; region dead
#pragma unroll
    for (int q = 0; q < 4; q++) {
        const int mt = q * 4 + wave;
        const int n0 = mt * 16 + quad * 4;
        f32x4 b4 = *(const f32x4*)(fc2_b + n0);
#pragma unroll
        for (int nt = 0; nt < 4; nt++) {
            float x0 = fmaxf(acc2[q][nt][0] + b4[0], 0.f);
            float x1 = fmaxf(acc2[q][nt][1] + b4[1], 0.f);
            float x2 = fmaxf(acc2[q][nt][2] + b4[2], 0.f);
            float x3 = fmaxf(acc2[q][nt][3] + b4[3], 0.f);
            uint2v d;
            d.x = cvt_pk_bf16(x0, x1);
            d.y = cvt_pk_bf16(x2, x3);
            *(uint2v*)(X3f + ((n0 >> 3) * 64 + nt * 16 + mrow) * 8 + (n0 & 7)) = d;
        }
    }
    __syncthreads();  // barrier 3: X3full ready
    f32x4 acc3[2][4];
#pragma unroll
    for (int a = 0; a < 2; a++)
#pragma unroll
        for (int b = 0; b < 4; b++) acc3[a][b] = (f32x4){0.f, 0.f, 0.f, 0.f};
#pragma unroll
    for (int ks = 0; ks < 8; ks++) {
        short8 bfr[4];
#pragma unroll
        for (int nt = 0; nt < 4; nt++)
            bfr[nt] = *(const short8*)(X3f + ((ks * 4 + quad) * 64 + nt * 16 + mrow) * 8);
#pragma unroll
        for (int mtl = 0; mtl < 2; mtl++) {
            const int mt = wave * 2 + mtl;
            short8 ah = W3v[(mt * 8 + ks) * 64 + lane];
#pragma unroll
            for (int nt = 0; nt < 4; nt++)
                acc3[mtl][nt] = __builtin_amdgcn_mfma_f32_16x16x32_bf16(ah, bfr[nt], acc3[mtl][nt], 0, 0, 0);
        }
    }
    {
        float p4[4] = {0.f, 0.f, 0.f, 0.f};
#pragma unroll
        for (int mtl = 0; mtl < 2; mtl++) {
            const int mt = wave * 2 + mtl;
            const int n0 = mt * 16 + quad * 4;
            f32x4 b4 = *(const f32x4*)(fc3_b + n0);
            f32x4 w44 = *(const f32x4*)(fc4_w + n0);
#pragma unroll
            for (int nt = 0; nt < 4; nt++)
#pragma unroll
                for (int r = 0; r < 4; r++)
                    p4[nt] = fmaf(fmaxf(acc3[mtl][nt][r] + b4[r], 0.f), w44[r], p4[nt]);
        }
#pragma unroll
        for (int nt = 0; nt < 4; nt++) {
            p4[nt] += __shfl_xor(p4[nt], 16, 64);
            p4[nt] += __shfl_xor(p4[nt], 32, 64);
        }
        if (quad == 0) {
#pragma unroll
            for (int nt = 0; nt < 4; nt++)
                part[wave * 64 + nt * 16 + mrow] = p4[nt];
        }
    }
    __syncthreads();  // barrier 4: part ready
    if (tid < 64) {
        float pred = part[tid] + part[64 + tid] + part[128 + tid] + part[192 + tid] + fc4_b[0];
        preds[p * 256 + e0 + tid] = pred;
    }
}

// ---------------- Kernel 1 (fallback path): r10 monolithic, proven 65.5us ----------------
__global__ __launch_bounds__(256, 4)
void mlp_kernel(const float* __restrict__ G, const float* __restrict__ H,
                const float* __restrict__ w2, const float* __restrict__ b2,
                const float* __restrict__ w3, const float* __restrict__ b3,
                const float* __restrict__ fc1_b, const float* __restrict__ fc2_b,
                const float* __restrict__ fc3_b,
                const float* __restrict__ fc4_w, const float* __restrict__ fc4_b,
                const unsigned short* __restrict__ W1p, const unsigned short* __restrict__ W2p,
                const unsigned short* __restrict__ W3p,
                float* __restrict__ preds) {
    __shared__ __align__(16) float smem[8448];
    unsigned short* X1 = (unsigned short*)smem;
    unsigned short* X3f = (unsigned short*)smem;
    unsigned short* X2 = (unsigned short*)(smem + 4096);
    float* part = smem + 8192;

    const int tid = threadIdx.x;
    const int bid = (blockIdx.x & 7) * 512 + (blockIdx.x >> 3);
    const int p = bid >> 2;
    const int e0 = (bid & 3) * 64;
    const int s = p >> 5, t = p & 31;
    if (s == t) return;

    const int lane = tid & 63, wave = tid >> 6;
    const int mrow = lane & 15, quad = lane >> 4;
    const int gsample = tid >> 2, o = tid & 3;

    {
        uint2v d = conv_body(G, H, w2, b2, w3, b3, p, e0 + gsample, o);
        *(uint2v*)(X1 + (((o >> 1) * 64 + gsample) * 8) + (o & 1) * 4) = d;
        uint2v z2 = (uint2v){0u, 0u};
        *(uint2v*)(X1 + ((((o >> 1) + 2) * 64 + gsample) * 8) + (o & 1) * 4) = z2;
    }
    const short8* W1v = (const short8*)W1p;
    short8 w1f[2];
#pragma unroll
    for (int mtl = 0; mtl < 2; mtl++)
        w1f[mtl] = W1v[(wave * 2 + mtl) * 64 + lane];
    __syncthreads();
    {
        short8 bnt[4];
#pragma unroll
        for (int nt = 0; nt < 4; nt++)
            bnt[nt] = *(const short8*)(X1 + (quad * 64 + nt * 16 + mrow) * 8);
        f32x4 acc1[2][4];
#pragma unroll
        for (int a = 0; a < 2; a++)
#pragma unroll
            for (int b = 0; b < 4; b++) acc1[a][b] = (f32x4){0.f, 0.f, 0.f, 0.f};
#pragma unroll
        for (int mtl = 0; mtl < 2; mtl++) {
#pragma unroll
            for (int nt = 0; nt < 4; nt++)
                acc1[mtl][nt] = __builtin_amdgcn_mfma_f32_16x16x32_bf16(w1f[mtl], bnt[nt], acc1[mtl][nt], 0, 0, 0);
        }
#pragma unroll
        for (int mtl = 0; mtl < 2; mtl++) {
            const int mt = wave * 2 + mtl;
            const int n0 = mt * 16 + quad * 4;
            f32x4 b4 = *(const f32x4*)(fc1_b + n0);
#pragma unroll
            for (int nt = 0; nt < 4; nt++) {
                float x0 = fmaxf(acc1[mtl][nt][0] + b4[0], 0.f);
                float x1 = fmaxf(acc1[mtl][nt][1] + b4[1], 0.f);
                float x2 = fmaxf(acc1[mtl][nt][2] + b4[2], 0.f);
                float x3 = fmaxf(acc1[mtl][nt][3] + b4[3], 0.f);
                uint2v d;
                d.x = cvt_pk_bf16(x0, x1);
                d.y = cvt_pk_bf16(x2, x3);
                *(uint2v*)(X2 + ((n0 >> 3) * 64 + nt * 16 + mrow) * 8 + (n0 & 7)) = d;
            }
        }
    }
    __syncthreads();
    const short8* W2v = (const short8*)W2p;
    const short8* W3v = (const short8*)W3p;
    f32x4 acc2[4][4];
#pragma unroll
    for (int a = 0; a < 4; a++)
#pragma unroll
        for (int b = 0; b < 4; b++) acc2[a][b] = (f32x4){0.f, 0.f, 0.f, 0.f};
#pragma unroll
    for (int ks = 0; ks < 4; ks++) {
        short8 bfr[4];
#pragma unroll
        for (int nt = 0; nt < 4; nt++)
            bfr[nt] = *(const short8*)(X2 + ((ks * 4 + quad) * 64 + nt * 16 + mrow) * 8);
#pragma unroll
        for (int q = 0; q < 4; q++) {
            const int mt = q * 4 + wave;
            short8 ah = W2v[(mt * 4 + ks) * 64 + lane];
#pragma unroll
            for (int nt = 0; nt < 4; nt++)
                acc2[q][nt] = __builtin_amdgcn_mfma_f32_16x16x32_bf16(ah, bfr[nt], acc2[q][nt], 0, 0, 0);
        }
    }
    __syncthreads();
#pragma unroll
    for (int q = 0; q < 4; q++) {
        const int mt = q * 4 + wave;
        const int n0 = mt * 16 + quad * 4;
        f32x4 b4 = *(const f32x4*)(fc2_b + n0);
#pragma unroll
        for (int nt = 0; nt < 4; nt++) {
            float x0 = fmaxf(acc2[q][nt][0] + b4[0], 0.f);
            float x1 = fmaxf(acc2[q][nt][1] + b4[1], 0.f);
            float x2 = fmaxf(acc2[q][nt][2] + b4[2], 0.f);
            float x3 = fmaxf(acc2[q][nt][3] + b4[3], 0.f);
            uint2v d;
            d.x = cvt_pk_bf16(x0, x1);
            d.y = cvt_pk_bf16(x2, x3);
            *(uint2v*)(X3f + ((n0 >> 3) * 64 + nt * 16 + mrow) * 8 + (n0 & 7)) = d;
        }
    }
    __syncthreads();
    f32x4 acc3[2][4];
#pragma unroll
    for (int a = 0; a < 2; a++)
#pragma unroll
        for (int b = 0; b < 4; b++) acc3[a][b] = (f32x4){0.f, 0.f, 0.f, 0.f};
#pragma unroll
    for (int ks = 0; ks < 8; ks++) {
        short8 bfr[4];
#pragma unroll
        for (int nt = 0; nt < 4; nt++)
            bfr[nt] = *(const short8*)(X3f + ((ks * 4 + quad) * 64 + nt * 16 + mrow) * 8);
#pragma unroll
        for (int mtl = 0; mtl < 2; mtl++) {
            const int mt = wave * 2 + mtl;
            short8 ah = W3v[(mt * 8 + ks) * 64 + lane];
#pragma unroll
            for (int nt = 0; nt < 4; nt++)
                acc3[mtl][nt] = __builtin_amdgcn_mfma_f32_16x16x32_bf16(ah, bfr[nt], acc3[mtl][nt], 0, 0, 0);
        }
    }
    {
        float p4[4] = {0.f, 0.f, 0.f, 0.f};
#pragma unroll
        for (int mtl = 0; mtl < 2; mtl++) {
            const int mt = wave * 2 + mtl;
            const int n0 = mt * 16 + quad * 4;
            f32x4 b4 = *(const f32x4*)(fc3_b + n0);
            f32x4 w44 = *(const f32x4*)(fc4_w + n0);
#pragma unroll
            for (int nt = 0; nt < 4; nt++)
#pragma unroll
                for (int r = 0; r < 4; r++)
                    p4[nt] = fmaf(fmaxf(acc3[mtl][nt][r] + b4[r], 0.f), w44[r], p4[nt]);
        }
#pragma unroll
        for (int nt = 0; nt < 4; nt++) {
            p4[nt] += __shfl_xor(p4[nt], 16, 64);
            p4[nt] += __shfl_xor(p4[nt], 32, 64);
        }
        if (quad == 0) {
#pragma unroll
            for (int nt = 0; nt < 4; nt++)
                part[wave * 64 + nt * 16 + mrow] = p4[nt];
        }
    }
    __syncthreads();
    if (tid < 64) {
        float pred = part[tid] + part[64 + tid] + part[128 + tid] + part[192 + tid] + fc4_b[0];
        preds[p * 256 + e0 + tid] = pred;
    }
}

// ---------------- Kernel 2: propagation only, one WAVE per pair (256 blocks). ----------------
__global__ __launch_bounds__(256)
void prop_kernel(const int* __restrict__ edges, const float* __restrict__ preds,
                 float* __restrict__ rbc_part) {
    const int tid = threadIdx.x;
    const int wave = tid >> 6, lane = tid & 63;
    const int p = blockIdx.x * 4 + wave;
    const int s = p >> 5, t = p & 31;
    __shared__ float xw[4][32], xnw[4][32], raccw[4][32];
    int u[4], v[4];
    float pr[4];
#pragma unroll
    for (int j = 0; j < 4; j++) {
        int e = lane + 64 * j;
        u[j] = edges[2 * e];
        v[j] = edges[2 * e + 1];
        pr[j] = preds[p * 256 + e];
    }
    if (lane < 32) { xw[wave][lane] = (lane == s) ? 1.f : 0.f; raccw[wave][lane] = 0.f; }
    const bool active = (s != t);
    for (int step = 0; step < 3; step++) {
        if (lane < 32) xnw[wave][lane] = 0.f;
        __syncthreads();
        if (active) {
#pragma unroll
            for (int j = 0; j < 4; j++)
                atomicAdd(&xnw[wave][v[j]], xw[wave][u[j]] * pr[j]);
        }
        __syncthreads();
        if (lane < 32) { raccw[wave][lane] += xnw[wave][lane]; xw[wave][lane] = xnw[wave][lane]; }
        __syncthreads();
    }
    if (active && lane < 32) atomicAdd(&rbc_part[(p & 63) * 32 + lane], raccw[wave][lane]);
}

// ---------------- Kernel 3: final reduce + normalize (1 block). ----------------
__global__ __launch_bounds__(256)
void norm_kernel(const float* __restrict__ rbc_part, float* __restrict__ out) {
    const int tid = threadIdx.x;
    const int node = tid & 31, sub = tid >> 5;
    __shared__ float red[8][32];
    float vv = 0.f;
#pragma unroll
    for (int g = 0; g < 8; g++)
        vv += rbc_part[(sub * 8 + g) * 32 + node];
    red[sub][node] = vv;
    __syncthreads();
    if (tid < 32) {
        float acc = 0.f;
#pragma unroll
        for (int sb = 0; sb < 8; sb++) acc += red[sb][tid];
        float tot = acc;
#pragma unroll
        for (int mask = 1; mask < 32; mask <<= 1) tot += __shfl_xor(tot, mask, 32);
        out[tid] = acc / tot;
    }
}

extern "C" void kernel_launch(void* const* d_in, const int* in_sizes, int n_in,
                              void* d_out, int out_size, void* d_ws, size_t ws_size,
                              hipStream_t stream) {
    const float* emb = (const float*)d_in[0];
    const int* edges = (const int*)d_in[1];
    const float* w1 = (const float*)d_in[2];
    const float* b1 = (const float*)d_in[3];
    const float* w2 = (const float*)d_in[4];
    const float* b2 = (const float*)d_in[5];
    const float* w3 = (const float*)d_in[6];
    const float* b3 = (const float*)d_in[7];
    const float* fc1_w = (const float*)d_in[8];
    const float* fc1_b = (const float*)d_in[9];
    const float* fc2_w = (const float*)d_in[10];
    const float* fc2_b = (const float*)d_in[11];
    const float* fc3_w = (const float*)d_in[12];
    const float* fc3_b = (const float*)d_in[13];
    const float* fc4_w = (const float*)d_in[14];
    const float* fc4_b = (const float*)d_in[15];

    float* ws = (float*)d_ws;
    float* G = ws + G_OFF;
    float* H = ws + H_OFF;
    float* preds = ws + PREDS_OFF;
    float* rbc_part = ws + RBCP_OFF;
    unsigned short* W1p = (unsigned short*)(ws + W1P_OFF);
    unsigned short* W2p = (unsigned short*)(ws + W2P_OFF);
    unsigned short* W3p = (unsigned short*)(ws + W3P_OFF);
    unsigned short* C1 = (unsigned short*)(ws + C1_OFF);
    float* out = (float*)d_out;

    prep_all<<<dim3(1233), dim3(256), 0, stream>>>(emb, edges, w1, b1, fc1_w, fc2_w, fc3_w,
                                                   G, H, W1p, W2p, W3p, rbc_part);
    if (ws_size >= SPLIT_WS_FLOATS * sizeof(float)) {
        conv_kernel<<<dim3(4096), dim3(256), 0, stream>>>(G, H, w2, b2, w3, b3, C1);
        fc_kernel<<<dim3(4096), dim3(256), 0, stream>>>(
            C1, fc1_b, fc2_b, fc3_b, fc4_w, fc4_b, W1p, W2p, W3p, preds);
    } else {
        mlp_kernel<<<dim3(4096), dim3(256), 0, stream>>>(
            G, H, w2, b2, w3, b3, fc1_b, fc2_b, fc3_b,
            fc4_w, fc4_b, W1p, W2p, W3p, preds);
    }
    prop_kernel<<<dim3(256), dim3(256), 0, stream>>>(edges, preds, rbc_part);
    norm_kernel<<<dim3(1), dim3(256), 0, stream>>>(rbc_part, out);
}

// Round 13
// 165.608 us; speedup vs baseline: 1.0243x; 1.0243x over previous
//
#include <hip/hip_runtime.h>

// ---- ws layout (float offsets) ----
// G: per-pair conv1 tables [1024][4][48] (F_s + F_t)           = 196608 floats
// H: per-edge conv1 tables [256][4][48]  (F_u + F_v + b1)      = 49152 floats
constexpr int G_OFF = 0;
constexpr int H_OFF = 196608;
constexpr int PREDS_OFF = H_OFF + 49152;        // 245760
constexpr int RBCP_OFF = PREDS_OFF + 262144;    // 507904: rbc_part[64][32]
constexpr int CNT_OFF = RBCP_OFF + 2048;        // 509952 (legacy pad)
constexpr int W1P_OFF = CNT_OFF + 16;           // 509968: fc1 A-frags 4096 shorts
constexpr int W2P_OFF = W1P_OFF + 2048;         // 512016: fc2 A-frags 32768 shorts
constexpr int W3P_OFF = W2P_OFF + 16384;        // 528400: fc3 A-frags 32768 shorts
constexpr int BASE_FLOATS = 544784;
// C1: conv3 output staging [4096 blocks][2][64][8] shorts = 4 Mi shorts = 2 Mi floats
constexpr int C1_OFF = BASE_FLOATS;
constexpr size_t SPLIT_WS_FLOATS = (size_t)BASE_FLOATS + 4096 * 512;  // 512 f/block

typedef __attribute__((ext_vector_type(8))) short short8;
typedef __attribute__((ext_vector_type(4))) short short4v;
typedef __attribute__((ext_vector_type(4))) float f32x4;
typedef __attribute__((ext_vector_type(2))) unsigned int uint2v;

__device__ __forceinline__ unsigned short f2bf(float x) {  // RNE bf16 (prep only)
    unsigned u = __float_as_uint(x);
    u += 0x7FFF + ((u >> 16) & 1);
    return (unsigned short)(u >> 16);
}

// One-instruction packed f32->bf16 pair (low = a, high = b).
__device__ __forceinline__ unsigned cvt_pk_bf16(float a, float b) {
    unsigned r;
    asm("v_cvt_pk_bf16_f32 %0, %1, %2" : "=v"(r) : "v"(a), "v"(b));
    return r;
}

// quad_perm DPP: lane -> lane^m within each 4-lane quad (VALU, no LDS pipe).
template <int CTRL>
__device__ __forceinline__ float qp(float x) {
    return __int_as_float(__builtin_amdgcn_update_dpp(
        0, __float_as_int(x), CTRL, 0xF, 0xF, true));
}

// ---------------- Kernel 0: all preprocessing ----------------
__global__ void prep_all(const float* __restrict__ emb, const int* __restrict__ edges,
                         const float* __restrict__ w1, const float* __restrict__ b1,
                         const float* __restrict__ fc1_w, const float* __restrict__ fc2_w,
                         const float* __restrict__ fc3_w,
                         float* __restrict__ G, float* __restrict__ H,
                         unsigned short* __restrict__ W1p,
                         unsigned short* __restrict__ W2p, unsigned short* __restrict__ W3p,
                         float* __restrict__ rbcp_zero) {
    int b = blockIdx.x;
    if (b < 768) {  // G[p][o][i] = conv1 contribution of (s as c0) + (t as c1)
        int idx = b * 256 + threadIdx.x;  // 196608
        int i = idx % 48;
        int o = (idx / 48) & 3;
        int p = idx / 192;
        int s = p >> 5, t = p & 31;
        float acc = 0.f;
        if (i < 46) {
#pragma unroll
            for (int k = 0; k < 3; k++)
                acc += w1[(o * 4 + 0) * 3 + k] * emb[s * 96 + 2 * i + k] +
                       w1[(o * 4 + 1) * 3 + k] * emb[t * 96 + 2 * i + k];
        }
        G[idx] = acc;
        return;
    }
    if (b < 960) {  // H[e][o][i] = conv1 contribution of (u as c2) + (v as c3) + b1[o]
        int idx = (b - 768) * 256 + threadIdx.x;  // 49152
        int i = idx % 48;
        int o = (idx / 48) & 3;
        int e = idx / 192;
        int u = edges[2 * e], v = edges[2 * e + 1];
        float acc = 0.f;
        if (i < 46) {
            acc = b1[o];
#pragma unroll
            for (int k = 0; k < 3; k++)
                acc += w1[(o * 4 + 2) * 3 + k] * emb[u * 96 + 2 * i + k] +
                       w1[(o * 4 + 3) * 3 + k] * emb[v * 96 + 2 * i + k];
        }
        H[idx] = acc;
        return;
    }
    if (b < 976) {  // fc1 A-layout, K padded 16->32, single bf16
        int t = (b - 960) * 256 + threadIdx.x;  // 4096
        int j = t & 7, lane = (t >> 3) & 63, mt = t >> 9;
        int k = (lane >> 4) * 8 + j, n = mt * 16 + (lane & 15);
        float w = (k < 16) ? fc1_w[k * 128 + n] : 0.f;
        W1p[t] = f2bf(w);
        return;
    }
    if (b < 1104) {  // fc2 A-layout [16mt][4ks], single bf16
        int t = (b - 976) * 256 + threadIdx.x;  // 32768
        int j = t & 7, lane = (t >> 3) & 63, ks = (t >> 9) & 3, mt = t >> 11;
        int k = ks * 32 + (lane >> 4) * 8 + j, n = mt * 16 + (lane & 15);
        W2p[t] = f2bf(fc2_w[k * 256 + n]);
        return;
    }
    if (b < 1232) {  // fc3 A-layout [8mt][8ks], single bf16
        int t = (b - 1104) * 256 + threadIdx.x;  // 32768
        int j = t & 7, lane = (t >> 3) & 63, ks = (t >> 9) & 7, mt = t >> 12;
        int k = ks * 32 + (lane >> 4) * 8 + j, n = mt * 16 + (lane & 15);
        W3p[t] = f2bf(fc3_w[k * 128 + n]);
        return;
    }
    for (int k = threadIdx.x; k < 2064; k += 256) rbcp_zero[k] = 0.f;
}

// ====== Shared conv body, register-lean: pool+relu FUSED into producer loops ======
// (r12 lesson: pre[46]/pre[20]/pre[8] arrays pushed live set >64 -> scratch spill
// in the standalone conv kernel. Fused pooling keeps peak live ~55 regs.)
__device__ __forceinline__ uint2v conv_body(
        const float* __restrict__ G, const float* __restrict__ H,
        const float* __restrict__ w2, const float* __restrict__ b2,
        const float* __restrict__ w3, const float* __restrict__ b3,
        int p, int e, int o) {
    float h1[23];
    {
        const f32x4* Gp = (const f32x4*)(G + (p * 4 + o) * 48);
        const f32x4* Hp = (const f32x4*)(H + (e * 4 + o) * 48);
#pragma unroll
        for (int q = 0; q < 12; q++) {
            f32x4 x = Gp[q] + Hp[q];
            h1[2 * q] = fmaxf(fmaxf(x[0], x[1]), 0.f);
            if (2 * q + 1 < 23) h1[2 * q + 1] = fmaxf(fmaxf(x[2], x[3]), 0.f);
        }
    }
    float h2[10];
    {
        float wm[4][3];  // wm[m][k] = w2[o][o^m][k]
#pragma unroll
        for (int m = 0; m < 4; m++)
#pragma unroll
            for (int k = 0; k < 3; k++) wm[m][k] = w2[o * 12 + (o ^ m) * 3 + k];
        const float bb = b2[o];
        float win[4][3];
#pragma unroll
        for (int j = 0; j < 2; j++) {
            float x = h1[j];
            win[0][j] = x;
            win[1][j] = qp<0xB1>(x);
            win[2][j] = qp<0x4E>(x);
            win[3][j] = qp<0x1B>(x);
        }
        float evenv = 0.f;
#pragma unroll
        for (int i = 0; i < 20; i++) {
            float x = h1[i + 2];
            win[0][(i + 2) % 3] = x;
            win[1][(i + 2) % 3] = qp<0xB1>(x);
            win[2][(i + 2) % 3] = qp<0x4E>(x);
            win[3][(i + 2) % 3] = qp<0x1B>(x);
            float acc = bb;
#pragma unroll
            for (int m = 0; m < 4; m++)
#pragma unroll
                for (int k = 0; k < 3; k++)
                    acc = fmaf(wm[m][k], win[m][(i + k) % 3], acc);
            if ((i & 1) == 0) evenv = acc;
            else h2[i >> 1] = fmaxf(fmaxf(evenv, acc), 0.f);
        }
    }
    {
        float wm[4][3];
#pragma unroll
        for (int m = 0; m < 4; m++)
#pragma unroll
            for (int k = 0; k < 3; k++) wm[m][k] = w3[o * 12 + (o ^ m) * 3 + k];
        const float bb = b3[o];
        float win[4][3];
#pragma unroll
        for (int j = 0; j < 2; j++) {
            float x = h2[j];
            win[0][j] = x;
            win[1][j] = qp<0xB1>(x);
            win[2][j] = qp<0x4E>(x);
            win[3][j] = qp<0x1B>(x);
        }
        float v[4];
        float evenv = 0.f;
#pragma unroll
        for (int i = 0; i < 8; i++) {
            float x = h2[i + 2];
            win[0][(i + 2) % 3] = x;
            win[1][(i + 2) % 3] = qp<0xB1>(x);
            win[2][(i + 2) % 3] = qp<0x4E>(x);
            win[3][(i + 2) % 3] = qp<0x1B>(x);
            float acc = bb;
#pragma unroll
            for (int m = 0; m < 4; m++)
#pragma unroll
                for (int k = 0; k < 3; k++)
                    acc = fmaf(wm[m][k], win[m][(i + k) % 3], acc);
            if ((i & 1) == 0) evenv = acc;
            else v[i >> 1] = fmaxf(fmaxf(evenv, acc), 0.f);
        }
        uint2v d;
        d.x = cvt_pk_bf16(v[0], v[1]);
        d.y = cvt_pk_bf16(v[2], v[3]);
        return d;
    }
}

// ---------------- Kernel 1a (split path): conv only. No LDS, no barriers, no MFMA.
// launch_bounds(256, 6): ~85-reg budget (lean body needs ~55) -> 6 waves/SIMD,
// 1.5x the fused kernel's residency, no spill.
__global__ __launch_bounds__(256, 6)
void conv_kernel(const float* __restrict__ G, const float* __restrict__ H,
                 const float* __restrict__ w2, const float* __restrict__ b2,
                 const float* __restrict__ w3, const float* __restrict__ b3,
                 unsigned short* __restrict__ C1) {
    const int bid = (blockIdx.x & 7) * 512 + (blockIdx.x >> 3);  // XCD swizzle
    const int p = bid >> 2;
    const int e0 = (bid & 3) * 64;
    const int s = p >> 5, t = p & 31;
    if (s == t) return;
    const int tid = threadIdx.x;
    const int gsample = tid >> 2, o = tid & 3;
    uint2v d = conv_body(G, H, w2, b2, w3, b3, p, e0 + gsample, o);
    unsigned short* C1b = C1 + (size_t)bid * 1024;
    *(uint2v*)(C1b + (((o >> 1) * 64 + gsample) * 8) + (o & 1) * 4) = d;
}

// ---------------- Kernel 1b (split path): fc1..fc4. B-frag for fc1 from global C1.
__global__ __launch_bounds__(256, 4)
void fc_kernel(const unsigned short* __restrict__ C1,
               const float* __restrict__ fc1_b, const float* __restrict__ fc2_b,
               const float* __restrict__ fc3_b,
               const float* __restrict__ fc4_w, const float* __restrict__ fc4_b,
               const unsigned short* __restrict__ W1p, const unsigned short* __restrict__ W2p,
               const unsigned short* __restrict__ W3p,
               float* __restrict__ preds) {
    __shared__ __align__(16) float smem[8448];
    unsigned short* X3f = (unsigned short*)smem;
    unsigned short* X2 = (unsigned short*)(smem + 4096);
    float* part = smem + 8192;

    const int tid = threadIdx.x;
    const int bid = (blockIdx.x & 7) * 512 + (blockIdx.x >> 3);  // XCD swizzle
    const int p = bid >> 2;
    const int e0 = (bid & 3) * 64;
    const int s = p >> 5, t = p & 31;
    if (s == t) return;

    const int lane = tid & 63, wave = tid >> 6;
    const int mrow = lane & 15, quad = lane >> 4;

    // ---- fc1 MFMA: A=W1p, B from C1 (quad>=2 lanes hold the K-padding zeros) ----
    {
        const short8* W1v = (const short8*)W1p;
        short8 w1f[2];
#pragma unroll
        for (int mtl = 0; mtl < 2; mtl++)
            w1f[mtl] = W1v[(wave * 2 + mtl) * 64 + lane];
        const unsigned short* C1b = C1 + (size_t)bid * 1024;
        const short8 z8 = (short8){0, 0, 0, 0, 0, 0, 0, 0};
        short8 bnt[4];
#pragma unroll
        for (int nt = 0; nt < 4; nt++)
            bnt[nt] = (quad < 2) ? *(const short8*)(C1b + (quad * 64 + nt * 16 + mrow) * 8) : z8;
        f32x4 acc1[2][4];
#pragma unroll
        for (int a = 0; a < 2; a++)
#pragma unroll
            for (int b = 0; b < 4; b++) acc1[a][b] = (f32x4){0.f, 0.f, 0.f, 0.f};
#pragma unroll
        for (int mtl = 0; mtl < 2; mtl++) {
#pragma unroll
            for (int nt = 0; nt < 4; nt++)
                acc1[mtl][nt] = __builtin_amdgcn_mfma_f32_16x16x32_bf16(w1f[mtl], bnt[nt], acc1[mtl][nt], 0, 0, 0);
        }
#pragma unroll
        for (int mtl = 0; mtl < 2; mtl++) {
            const int mt = wave * 2 + mtl;
            const int n0 = mt * 16 + quad * 4;
            f32x4 b4 = *(const f32x4*)(fc1_b + n0);
#pragma unroll
            for (int nt = 0; nt < 4; nt++) {
                float x0 = fmaxf(acc1[mtl][nt][0] + b4[0], 0.f);
                float x1 = fmaxf(acc1[mtl][nt][1] + b4[1], 0.f);
                float x2 = fmaxf(acc1[mtl][nt][2] + b4[2], 0.f);
                float x3 = fmaxf(acc1[mtl][nt][3] + b4[3], 0.f);
                uint2v d;
                d.x = cvt_pk_bf16(x0, x1);
                d.y = cvt_pk_bf16(x2, x3);
                *(uint2v*)(X2 + ((n0 >> 3) * 64 + nt * 16 + mrow) * 8 + (n0 & 7)) = d;
            }
        }
    }
    __syncthreads();  // barrier 1: X2 ready
    const short8* W2v = (const short8*)W2p;
    const short8* W3v = (const short8*)W3p;
    f32x4 acc2[4][4];
#pragma unroll
    for (int a = 0; a < 4; a++)
#pragma unroll
        for (int b = 0; b < 4; b++) acc2[a][b] = (f32x4){0.f, 0.f, 0.f, 0.f};
#pragma unroll
    for (int ks = 0; ks < 4; ks++) {
        short8 bfr[4];
#pragma unroll
        for (int nt = 0; nt < 4; nt++)
            bfr[nt] = *(const short8*)(X2 + ((ks * 4 + quad) * 64 + nt * 16 + mrow) * 8);
#pragma unroll
        for (int q = 0; q < 4; q++) {
            const int mt = q * 4 + wave;
            short8 ah = W2v[(mt * 4 + ks) * 64 + lane];
#pragma unroll
            for (int nt = 0; nt < 4; nt++)
                acc2[q][nt] = __builtin_amdgcn_mfma_f32_16x16x32_bf16(ah, bfr[nt], acc2[q][nt], 0, 0, 0);
        }
    }
    __syncthreads();  // barrier 2: X2 reads done; region dead
#pragma unroll
    for (int q = 0; q < 4; q++) {
        const int mt = q * 4 + wave;
        const int n0 = mt * 16 + quad * 4;
        f32x4 b4 = *(const f32x4*)(fc2_b + n0);
#pragma unroll
        for (int nt = 0; nt < 4; nt++) {
            float x0 = fmaxf(acc2[q][nt][0] + b4[0], 0.f);
            float x1 = fmaxf(acc2[q][nt][1] + b4[1], 0.f);
            float x2 = fmaxf(acc2[q][nt][2] + b4[2], 0.f);
            float x3 = fmaxf(acc2[q][nt][3] + b4[3], 0.f);
            uint2v d;
            d.x = cvt_pk_bf16(x0, x1);
            d.y = cvt_pk_bf16(x2, x3);
            *(uint2v*)(X3f + ((n0 >> 3) * 64 + nt * 16 + mrow) * 8 + (n0 & 7)) = d;
        }
    }
    __syncthreads();  // barrier 3: X3full ready
    f32x4 acc3[2][4];
#pragma unroll
    for (int a = 0; a < 2; a++)
#pragma unroll
        for (int b = 0; b < 4; b++) acc3[a][b] = (f32x4){0.f, 0.f, 0.f, 0.f};
#pragma unroll
    for (int ks = 0; ks < 8; ks++) {
        short8 bfr[4];
#pragma unroll
        for (int nt = 0; nt < 4; nt++)
            bfr[nt] = *(const short8*)(X3f + ((ks * 4 + quad) * 64 + nt * 16 + mrow) * 8);
#pragma unroll
        for (int mtl = 0; mtl < 2; mtl++) {
            const int mt = wave * 2 + mtl;
            short8 ah = W3v[(mt * 8 + ks) * 64 + lane];
#pragma unroll
            for (int nt = 0; nt < 4; nt++)
                acc3[mtl][nt] = __builtin_amdgcn_mfma_f32_16x16x32_bf16(ah, bfr[nt], acc3[mtl][nt], 0, 0, 0);
        }
    }
    {
        float p4[4] = {0.f, 0.f, 0.f, 0.f};
#pragma unroll
        for (int mtl = 0; mtl < 2; mtl++) {
            const int mt = wave * 2 + mtl;
            const int n0 = mt * 16 + quad * 4;
            f32x4 b4 = *(const f32x4*)(fc3_b + n0);
            f32x4 w44 = *(const f32x4*)(fc4_w + n0);
#pragma unroll
            for (int nt = 0; nt < 4; nt++)
#pragma unroll
                for (int r = 0; r < 4; r++)
                    p4[nt] = fmaf(fmaxf(acc3[mtl][nt][r] + b4[r], 0.f), w44[r], p4[nt]);
        }
#pragma unroll
        for (int nt = 0; nt < 4; nt++) {
            p4[nt] += __shfl_xor(p4[nt], 16, 64);
            p4[nt] += __shfl_xor(p4[nt], 32, 64);
        }
        if (quad == 0) {
#pragma unroll
            for (int nt = 0; nt < 4; nt++)
                part[wave * 64 + nt * 16 + mrow] = p4[nt];
        }
    }
    __syncthreads();  // barrier 4: part ready
    if (tid < 64) {
        float pred = part[tid] + part[64 + tid] + part[128 + tid] + part[192 + tid] + fc4_b[0];
        preds[p * 256 + e0 + tid] = pred;
    }
}

// ---------------- Kernel 1 (fallback path): r10 monolithic (lean conv body) ----------------
__global__ __launch_bounds__(256, 4)
void mlp_kernel(const float* __restrict__ G, const float* __restrict__ H,
                const float* __restrict__ w2, const float* __restrict__ b2,
                const float* __restrict__ w3, const float* __restrict__ b3,
                const float* __restrict__ fc1_b, const float* __restrict__ fc2_b,
                const float* __restrict__ fc3_b,
                const float* __restrict__ fc4_w, const float* __restrict__ fc4_b,
                const unsigned short* __restrict__ W1p, const unsigned short* __restrict__ W2p,
                const unsigned short* __restrict__ W3p,
                float* __restrict__ preds) {
    __shared__ __align__(16) float smem[8448];
    unsigned short* X1 = (unsigned short*)smem;
    unsigned short* X3f = (unsigned short*)smem;
    unsigned short* X2 = (unsigned short*)(smem + 4096);
    float* part = smem + 8192;

    const int tid = threadIdx.x;
    const int bid = (blockIdx.x & 7) * 512 + (blockIdx.x >> 3);
    const int p = bid >> 2;
    const int e0 = (bid & 3) * 64;
    const int s = p >> 5, t = p & 31;
    if (s == t) return;

    const int lane = tid & 63, wave = tid >> 6;
    const int mrow = lane & 15, quad = lane >> 4;
    const int gsample = tid >> 2, o = tid & 3;

    {
        uint2v d = conv_body(G, H, w2, b2, w3, b3, p, e0 + gsample, o);
        *(uint2v*)(X1 + (((o >> 1) * 64 + gsample) * 8) + (o & 1) * 4) = d;
        uint2v z2 = (uint2v){0u, 0u};
        *(uint2v*)(X1 + ((((o >> 1) + 2) * 64 + gsample) * 8) + (o & 1) * 4) = z2;
    }
    const short8* W1v = (const short8*)W1p;
    short8 w1f[2];
#pragma unroll
    for (int mtl = 0; mtl < 2; mtl++)
        w1f[mtl] = W1v[(wave * 2 + mtl) * 64 + lane];
    __syncthreads();
    {
        short8 bnt[4];
#pragma unroll
        for (int nt = 0; nt < 4; nt++)
            bnt[nt] = *(const short8*)(X1 + (quad * 64 + nt * 16 + mrow) * 8);
        f32x4 acc1[2][4];
#pragma unroll
        for (int a = 0; a < 2; a++)
#pragma unroll
            for (int b = 0; b < 4; b++) acc1[a][b] = (f32x4){0.f, 0.f, 0.f, 0.f};
#pragma unroll
        for (int mtl = 0; mtl < 2; mtl++) {
#pragma unroll
            for (int nt = 0; nt < 4; nt++)
                acc1[mtl][nt] = __builtin_amdgcn_mfma_f32_16x16x32_bf16(w1f[mtl], bnt[nt], acc1[mtl][nt], 0, 0, 0);
        }
#pragma unroll
        for (int mtl = 0; mtl < 2; mtl++) {
            const int mt = wave * 2 + mtl;
            const int n0 = mt * 16 + quad * 4;
            f32x4 b4 = *(const f32x4*)(fc1_b + n0);
#pragma unroll
            for (int nt = 0; nt < 4; nt++) {
                float x0 = fmaxf(acc1[mtl][nt][0] + b4[0], 0.f);
                float x1 = fmaxf(acc1[mtl][nt][1] + b4[1], 0.f);
                float x2 = fmaxf(acc1[mtl][nt][2] + b4[2], 0.f);
                float x3 = fmaxf(acc1[mtl][nt][3] + b4[3], 0.f);
                uint2v d;
                d.x = cvt_pk_bf16(x0, x1);
                d.y = cvt_pk_bf16(x2, x3);
                *(uint2v*)(X2 + ((n0 >> 3) * 64 + nt * 16 + mrow) * 8 + (n0 & 7)) = d;
            }
        }
    }
    __syncthreads();
    const short8* W2v = (const short8*)W2p;
    const short8* W3v = (const short8*)W3p;
    f32x4 acc2[4][4];
#pragma unroll
    for (int a = 0; a < 4; a++)
#pragma unroll
        for (int b = 0; b < 4; b++) acc2[a][b] = (f32x4){0.f, 0.f, 0.f, 0.f};
#pragma unroll
    for (int ks = 0; ks < 4; ks++) {
        short8 bfr[4];
#pragma unroll
        for (int nt = 0; nt < 4; nt++)
            bfr[nt] = *(const short8*)(X2 + ((ks * 4 + quad) * 64 + nt * 16 + mrow) * 8);
#pragma unroll
        for (int q = 0; q < 4; q++) {
            const int mt = q * 4 + wave;
            short8 ah = W2v[(mt * 4 + ks) * 64 + lane];
#pragma unroll
            for (int nt = 0; nt < 4; nt++)
                acc2[q][nt] = __builtin_amdgcn_mfma_f32_16x16x32_bf16(ah, bfr[nt], acc2[q][nt], 0, 0, 0);
        }
    }
    __syncthreads();
#pragma unroll
    for (int q = 0; q < 4; q++) {
        const int mt = q * 4 + wave;
        const int n0 = mt * 16 + quad * 4;
        f32x4 b4 = *(const f32x4*)(fc2_b + n0);
#pragma unroll
        for (int nt = 0; nt < 4; nt++) {
            float x0 = fmaxf(acc2[q][nt][0] + b4[0], 0.f);
            float x1 = fmaxf(acc2[q][nt][1] + b4[1], 0.f);
            float x2 = fmaxf(acc2[q][nt][2] + b4[2], 0.f);
            float x3 = fmaxf(acc2[q][nt][3] + b4[3], 0.f);
            uint2v d;
            d.x = cvt_pk_bf16(x0, x1);
            d.y = cvt_pk_bf16(x2, x3);
            *(uint2v*)(X3f + ((n0 >> 3) * 64 + nt * 16 + mrow) * 8 + (n0 & 7)) = d;
        }
    }
    __syncthreads();
    f32x4 acc3[2][4];
#pragma unroll
    for (int a = 0; a < 2; a++)
#pragma unroll
        for (int b = 0; b < 4; b++) acc3[a][b] = (f32x4){0.f, 0.f, 0.f, 0.f};
#pragma unroll
    for (int ks = 0; ks < 8; ks++) {
        short8 bfr[4];
#pragma unroll
        for (int nt = 0; nt < 4; nt++)
            bfr[nt] = *(const short8*)(X3f + ((ks * 4 + quad) * 64 + nt * 16 + mrow) * 8);
#pragma unroll
        for (int mtl = 0; mtl < 2; mtl++) {
            const int mt = wave * 2 + mtl;
            short8 ah = W3v[(mt * 8 + ks) * 64 + lane];
#pragma unroll
            for (int nt = 0; nt < 4; nt++)
                acc3[mtl][nt] = __builtin_amdgcn_mfma_f32_16x16x32_bf16(ah, bfr[nt], acc3[mtl][nt], 0, 0, 0);
        }
    }
    {
        float p4[4] = {0.f, 0.f, 0.f, 0.f};
#pragma unroll
        for (int mtl = 0; mtl < 2; mtl++) {
            const int mt = wave * 2 + mtl;
            const int n0 = mt * 16 + quad * 4;
            f32x4 b4 = *(const f32x4*)(fc3_b + n0);
            f32x4 w44 = *(const f32x4*)(fc4_w + n0);
#pragma unroll
            for (int nt = 0; nt < 4; nt++)
#pragma unroll
                for (int r = 0; r < 4; r++)
                    p4[nt] = fmaf(fmaxf(acc3[mtl][nt][r] + b4[r], 0.f), w44[r], p4[nt]);
        }
#pragma unroll
        for (int nt = 0; nt < 4; nt++) {
            p4[nt] += __shfl_xor(p4[nt], 16, 64);
            p4[nt] += __shfl_xor(p4[nt], 32, 64);
        }
        if (quad == 0) {
#pragma unroll
            for (int nt = 0; nt < 4; nt++)
                part[wave * 64 + nt * 16 + mrow] = p4[nt];
        }
    }
    __syncthreads();
    if (tid < 64) {
        float pred = part[tid] + part[64 + tid] + part[128 + tid] + part[192 + tid] + fc4_b[0];
        preds[p * 256 + e0 + tid] = pred;
    }
}

// ---------------- Kernel 2: propagation only, one WAVE per pair (256 blocks). ----------------
__global__ __launch_bounds__(256)
void prop_kernel(const int* __restrict__ edges, const float* __restrict__ preds,
                 float* __restrict__ rbc_part) {
    const int tid = threadIdx.x;
    const int wave = tid >> 6, lane = tid & 63;
    const int p = blockIdx.x * 4 + wave;
    const int s = p >> 5, t = p & 31;
    __shared__ float xw[4][32], xnw[4][32], raccw[4][32];
    int u[4], v[4];
    float pr[4];
#pragma unroll
    for (int j = 0; j < 4; j++) {
        int e = lane + 64 * j;
        u[j] = edges[2 * e];
        v[j] = edges[2 * e + 1];
        pr[j] = preds[p * 256 + e];
    }
    if (lane < 32) { xw[wave][lane] = (lane == s) ? 1.f : 0.f; raccw[wave][lane] = 0.f; }
    const bool active = (s != t);
    for (int step = 0; step < 3; step++) {
        if (lane < 32) xnw[wave][lane] = 0.f;
        __syncthreads();
        if (active) {
#pragma unroll
            for (int j = 0; j < 4; j++)
                atomicAdd(&xnw[wave][v[j]], xw[wave][u[j]] * pr[j]);
        }
        __syncthreads();
        if (lane < 32) { raccw[wave][lane] += xnw[wave][lane]; xw[wave][lane] = xnw[wave][lane]; }
        __syncthreads();
    }
    if (active && lane < 32) atomicAdd(&rbc_part[(p & 63) * 32 + lane], raccw[wave][lane]);
}

// ---------------- Kernel 3: final reduce + normalize (1 block). ----------------
__global__ __launch_bounds__(256)
void norm_kernel(const float* __restrict__ rbc_part, float* __restrict__ out) {
    const int tid = threadIdx.x;
    const int node = tid & 31, sub = tid >> 5;
    __shared__ float red[8][32];
    float vv = 0.f;
#pragma unroll
    for (int g = 0; g < 8; g++)
        vv += rbc_part[(sub * 8 + g) * 32 + node];
    red[sub][node] = vv;
    __syncthreads();
    if (tid < 32) {
        float acc = 0.f;
#pragma unroll
        for (int sb = 0; sb < 8; sb++) acc += red[sb][tid];
        float tot = acc;
#pragma unroll
        for (int mask = 1; mask < 32; mask <<= 1) tot += __shfl_xor(tot, mask, 32);
        out[tid] = acc / tot;
    }
}

extern "C" void kernel_launch(void* const* d_in, const int* in_sizes, int n_in,
                              void* d_out, int out_size, void* d_ws, size_t ws_size,
                              hipStream_t stream) {
    const float* emb = (const float*)d_in[0];
    const int* edges = (const int*)d_in[1];
    const float* w1 = (const float*)d_in[2];
    const float* b1 = (const float*)d_in[3];
    const float* w2 = (const float*)d_in[4];
    const float* b2 = (const float*)d_in[5];
    const float* w3 = (const float*)d_in[6];
    const float* b3 = (const float*)d_in[7];
    const float* fc1_w = (const float*)d_in[8];
    const float* fc1_b = (const float*)d_in[9];
    const float* fc2_w = (const float*)d_in[10];
    const float* fc2_b = (const float*)d_in[11];
    const float* fc3_w = (const float*)d_in[12];
    const float* fc3_b = (const float*)d_in[13];
    const float* fc4_w = (const float*)d_in[14];
    const float* fc4_b = (const float*)d_in[15];

    float* ws = (float*)d_ws;
    float* G = ws + G_OFF;
    float* H = ws + H_OFF;
    float* preds = ws + PREDS_OFF;
    float* rbc_part = ws + RBCP_OFF;
    unsigned short* W1p = (unsigned short*)(ws + W1P_OFF);
    unsigned short* W2p = (unsigned short*)(ws + W2P_OFF);
    unsigned short* W3p = (unsigned short*)(ws + W3P_OFF);
    unsigned short* C1 = (unsigned short*)(ws + C1_OFF);
    float* out = (float*)d_out;

    prep_all<<<dim3(1233), dim3(256), 0, stream>>>(emb, edges, w1, b1, fc1_w, fc2_w, fc3_w,
                                                   G, H, W1p, W2p, W3p, rbc_part);
    if (ws_size >= SPLIT_WS_FLOATS * sizeof(float)) {
        conv_kernel<<<dim3(4096), dim3(256), 0, stream>>>(G, H, w2, b2, w3, b3, C1);
        fc_kernel<<<dim3(4096), dim3(256), 0, stream>>>(
            C1, fc1_b, fc2_b, fc3_b, fc4_w, fc4_b, W1p, W2p, W3p, preds);
    } else {
        mlp_kernel<<<dim3(4096), dim3(256), 0, stream>>>(
            G, H, w2, b2, w3, b3, fc1_b, fc2_b, fc3_b,
            fc4_w, fc4_b, W1p, W2p, W3p, preds);
    }
    prop_kernel<<<dim3(256), dim3(256), 0, stream>>>(edges, preds, rbc_part);
    norm_kernel<<<dim3(1), dim3(256), 0, stream>>>(rbc_part, out);
}

// Round 14
// 154.174 us; speedup vs baseline: 1.1003x; 1.0742x over previous
//
#include <hip/hip_runtime.h>

// ---- ws layout (float offsets) ----
// G: per-pair conv1 tables [1024][4][48] (F_s + F_t)           = 196608 floats
// H: per-edge conv1 tables [256][4][48]  (F_u + F_v + b1)      = 49152 floats
constexpr int G_OFF = 0;
constexpr int H_OFF = 196608;
constexpr int PREDS_OFF = H_OFF + 49152;        // 245760
constexpr int RBCP_OFF = PREDS_OFF + 262144;    // 507904: rbc_part[64][32]
constexpr int CNT_OFF = RBCP_OFF + 2048;        // 509952 (legacy pad)
constexpr int W1P_OFF = CNT_OFF + 16;           // 509968: fc1 A-frags 4096 shorts
constexpr int W2P_OFF = W1P_OFF + 2048;         // 512016: fc2 A-frags 32768 shorts
constexpr int W3P_OFF = W2P_OFF + 16384;        // 528400: fc3 A-frags 32768 shorts

typedef __attribute__((ext_vector_type(8))) short short8;
typedef __attribute__((ext_vector_type(4))) short short4v;
typedef __attribute__((ext_vector_type(4))) float f32x4;
typedef __attribute__((ext_vector_type(2))) unsigned int uint2v;

__device__ __forceinline__ unsigned short f2bf(float x) {  // RNE bf16 (prep only)
    unsigned u = __float_as_uint(x);
    u += 0x7FFF + ((u >> 16) & 1);
    return (unsigned short)(u >> 16);
}

// One-instruction packed f32->bf16 pair (low = a, high = b).
__device__ __forceinline__ unsigned cvt_pk_bf16(float a, float b) {
    unsigned r;
    asm("v_cvt_pk_bf16_f32 %0, %1, %2" : "=v"(r) : "v"(a), "v"(b));
    return r;
}

// quad_perm DPP: lane -> lane^m within each 4-lane quad (VALU, no LDS pipe).
template <int CTRL>
__device__ __forceinline__ float qp(float x) {
    return __int_as_float(__builtin_amdgcn_update_dpp(
        0, __float_as_int(x), CTRL, 0xF, 0xF, true));
}

// ---------------- Kernel 0: all preprocessing ----------------
__global__ void prep_all(const float* __restrict__ emb, const int* __restrict__ edges,
                         const float* __restrict__ w1, const float* __restrict__ b1,
                         const float* __restrict__ fc1_w, const float* __restrict__ fc2_w,
                         const float* __restrict__ fc3_w,
                         float* __restrict__ G, float* __restrict__ H,
                         unsigned short* __restrict__ W1p,
                         unsigned short* __restrict__ W2p, unsigned short* __restrict__ W3p,
                         float* __restrict__ rbcp_zero) {
    int b = blockIdx.x;
    if (b < 768) {  // G[p][o][i] = conv1 contribution of (s as c0) + (t as c1)
        int idx = b * 256 + threadIdx.x;  // 196608
        int i = idx % 48;
        int o = (idx / 48) & 3;
        int p = idx / 192;
        int s = p >> 5, t = p & 31;
        float acc = 0.f;
        if (i < 46) {
#pragma unroll
            for (int k = 0; k < 3; k++)
                acc += w1[(o * 4 + 0) * 3 + k] * emb[s * 96 + 2 * i + k] +
                       w1[(o * 4 + 1) * 3 + k] * emb[t * 96 + 2 * i + k];
        }
        G[idx] = acc;
        return;
    }
    if (b < 960) {  // H[e][o][i] = conv1 contribution of (u as c2) + (v as c3) + b1[o]
        int idx = (b - 768) * 256 + threadIdx.x;  // 49152
        int i = idx % 48;
        int o = (idx / 48) & 3;
        int e = idx / 192;
        int u = edges[2 * e], v = edges[2 * e + 1];
        float acc = 0.f;
        if (i < 46) {
            acc = b1[o];
#pragma unroll
            for (int k = 0; k < 3; k++)
                acc += w1[(o * 4 + 2) * 3 + k] * emb[u * 96 + 2 * i + k] +
                       w1[(o * 4 + 3) * 3 + k] * emb[v * 96 + 2 * i + k];
        }
        H[idx] = acc;
        return;
    }
    if (b < 976) {  // fc1 A-layout, K padded 16->32, single bf16
        int t = (b - 960) * 256 + threadIdx.x;  // 4096
        int j = t & 7, lane = (t >> 3) & 63, mt = t >> 9;
        int k = (lane >> 4) * 8 + j, n = mt * 16 + (lane & 15);
        float w = (k < 16) ? fc1_w[k * 128 + n] : 0.f;
        W1p[t] = f2bf(w);
        return;
    }
    if (b < 1104) {  // fc2 A-layout [16mt][4ks], single bf16
        int t = (b - 976) * 256 + threadIdx.x;  // 32768
        int j = t & 7, lane = (t >> 3) & 63, ks = (t >> 9) & 3, mt = t >> 11;
        int k = ks * 32 + (lane >> 4) * 8 + j, n = mt * 16 + (lane & 15);
        W2p[t] = f2bf(fc2_w[k * 256 + n]);
        return;
    }
    if (b < 1232) {  // fc3 A-layout [8mt][8ks], single bf16
        int t = (b - 1104) * 256 + threadIdx.x;  // 32768
        int j = t & 7, lane = (t >> 3) & 63, ks = (t >> 9) & 7, mt = t >> 12;
        int k = ks * 32 + (lane >> 4) * 8 + j, n = mt * 16 + (lane & 15);
        W3p[t] = f2bf(fc3_w[k * 128 + n]);
        return;
    }
    for (int k = threadIdx.x; k < 2064; k += 256) rbcp_zero[k] = 0.f;
}

// ====== Conv body, register-lean: pool+relu fused into producer loops ======
__device__ __forceinline__ uint2v conv_body(
        const float* __restrict__ G, const float* __restrict__ H,
        const float* __restrict__ w2, const float* __restrict__ b2,
        const float* __restrict__ w3, const float* __restrict__ b3,
        int p, int e, int o) {
    float h1[23];
    {
        const f32x4* Gp = (const f32x4*)(G + (p * 4 + o) * 48);
        const f32x4* Hp = (const f32x4*)(H + (e * 4 + o) * 48);
#pragma unroll
        for (int q = 0; q < 12; q++) {
            f32x4 x = Gp[q] + Hp[q];
            h1[2 * q] = fmaxf(fmaxf(x[0], x[1]), 0.f);
            if (2 * q + 1 < 23) h1[2 * q + 1] = fmaxf(fmaxf(x[2], x[3]), 0.f);
        }
    }
    float h2[10];
    {
        float wm[4][3];  // wm[m][k] = w2[o][o^m][k]
#pragma unroll
        for (int m = 0; m < 4; m++)
#pragma unroll
            for (int k = 0; k < 3; k++) wm[m][k] = w2[o * 12 + (o ^ m) * 3 + k];
        const float bb = b2[o];
        float win[4][3];
#pragma unroll
        for (int j = 0; j < 2; j++) {
            float x = h1[j];
            win[0][j] = x;
            win[1][j] = qp<0xB1>(x);
            win[2][j] = qp<0x4E>(x);
            win[3][j] = qp<0x1B>(x);
        }
        float evenv = 0.f;
#pragma unroll
        for (int i = 0; i < 20; i++) {
            float x = h1[i + 2];
            win[0][(i + 2) % 3] = x;
            win[1][(i + 2) % 3] = qp<0xB1>(x);
            win[2][(i + 2) % 3] = qp<0x4E>(x);
            win[3][(i + 2) % 3] = qp<0x1B>(x);
            float acc = bb;
#pragma unroll
            for (int m = 0; m < 4; m++)
#pragma unroll
                for (int k = 0; k < 3; k++)
                    acc = fmaf(wm[m][k], win[m][(i + k) % 3], acc);
            if ((i & 1) == 0) evenv = acc;
            else h2[i >> 1] = fmaxf(fmaxf(evenv, acc), 0.f);
        }
    }
    {
        float wm[4][3];
#pragma unroll
        for (int m = 0; m < 4; m++)
#pragma unroll
            for (int k = 0; k < 3; k++) wm[m][k] = w3[o * 12 + (o ^ m) * 3 + k];
        const float bb = b3[o];
        float win[4][3];
#pragma unroll
        for (int j = 0; j < 2; j++) {
            float x = h2[j];
            win[0][j] = x;
            win[1][j] = qp<0xB1>(x);
            win[2][j] = qp<0x4E>(x);
            win[3][j] = qp<0x1B>(x);
        }
        float v[4];
        float evenv = 0.f;
#pragma unroll
        for (int i = 0; i < 8; i++) {
            float x = h2[i + 2];
            win[0][(i + 2) % 3] = x;
            win[1][(i + 2) % 3] = qp<0xB1>(x);
            win[2][(i + 2) % 3] = qp<0x4E>(x);
            win[3][(i + 2) % 3] = qp<0x1B>(x);
            float acc = bb;
#pragma unroll
            for (int m = 0; m < 4; m++)
#pragma unroll
                for (int k = 0; k < 3; k++)
                    acc = fmaf(wm[m][k], win[m][(i + k) % 3], acc);
            if ((i & 1) == 0) evenv = acc;
            else v[i >> 1] = fmaxf(fmaxf(evenv, acc), 0.f);
        }
        uint2v d;
        d.x = cvt_pk_bf16(v[0], v[1]);
        d.y = cvt_pk_bf16(v[2], v[3]);
        return d;
    }
}

// ---------------- Kernel 1: monolithic (r10 structure, lean conv body, z8 K-pad).
// Phase decomposition (r13 split experiment): conv ~22us (VALU-issue floor),
// fc ~43us (MFMA floor ~13 + epilogue ~14 + stalls). Split itself is a DEAD END:
// C1 does an HBM round-trip (FETCH 7.1MB in fc), net +17us vs monolithic.
// Other dead ends: multi-chunk loop (spills), min-waves>=5 (spill), fused prop,
// one-block-per-pair, DPP-for-shfl (neutral), LDS-24K quarters (not LDS-limited;
// reg-file caps at VGPR+AGPR~128 -> 16 waves/CU), batched weight prefetch
// (compiler re-sinks), counter->extra-kernel (~1us), X3full 5-barrier (neutral),
// harness ws-poison fill (~43us x2, 268MB) is fixed overhead - not controllable.
__global__ __launch_bounds__(256, 4)
void mlp_kernel(const float* __restrict__ G, const float* __restrict__ H,
                const float* __restrict__ w2, const float* __restrict__ b2,
                const float* __restrict__ w3, const float* __restrict__ b3,
                const float* __restrict__ fc1_b, const float* __restrict__ fc2_b,
                const float* __restrict__ fc3_b,
                const float* __restrict__ fc4_w, const float* __restrict__ fc4_b,
                const unsigned short* __restrict__ W1p, const unsigned short* __restrict__ W2p,
                const unsigned short* __restrict__ W3p,
                float* __restrict__ preds) {
    // LDS (floats): X1 [0,512) real data only (K-pad synthesized in regs);
    // X2 [4096,8192); X3full [0,8192) after fc2 reads; part [8192,8448).
    __shared__ __align__(16) float smem[8448];
    unsigned short* X1 = (unsigned short*)smem;
    unsigned short* X3f = (unsigned short*)smem;
    unsigned short* X2 = (unsigned short*)(smem + 4096);
    float* part = smem + 8192;

    const int tid = threadIdx.x;
    const int bid = (blockIdx.x & 7) * 512 + (blockIdx.x >> 3);  // XCD swizzle
    const int p = bid >> 2;
    const int e0 = (bid & 3) * 64;
    const int s = p >> 5, t = p & 31;
    if (s == t) return;

    const int lane = tid & 63, wave = tid >> 6;
    const int mrow = lane & 15, quad = lane >> 4;
    const int gsample = tid >> 2, o = tid & 3;

    {
        uint2v d = conv_body(G, H, w2, b2, w3, b3, p, e0 + gsample, o);
        *(uint2v*)(X1 + (((o >> 1) * 64 + gsample) * 8) + (o & 1) * 4) = d;
        // no zero-stripe store: fc1 B-frag synthesizes K-pad zeros (z8, verified r13)
    }
    const short8* W1v = (const short8*)W1p;
    short8 w1f[2];
#pragma unroll
    for (int mtl = 0; mtl < 2; mtl++)
        w1f[mtl] = W1v[(wave * 2 + mtl) * 64 + lane];
    __syncthreads();  // barrier 1: X1 visible
    {
        const short8 z8 = (short8){0, 0, 0, 0, 0, 0, 0, 0};
        short8 bnt[4];
#pragma unroll
        for (int nt = 0; nt < 4; nt++)
            bnt[nt] = (quad < 2) ? *(const short8*)(X1 + (quad * 64 + nt * 16 + mrow) * 8) : z8;
        f32x4 acc1[2][4];
#pragma unroll
        for (int a = 0; a < 2; a++)
#pragma unroll
            for (int b = 0; b < 4; b++) acc1[a][b] = (f32x4){0.f, 0.f, 0.f, 0.f};
#pragma unroll
        for (int mtl = 0; mtl < 2; mtl++) {
#pragma unroll
            for (int nt = 0; nt < 4; nt++)
                acc1[mtl][nt] = __builtin_amdgcn_mfma_f32_16x16x32_bf16(w1f[mtl], bnt[nt], acc1[mtl][nt], 0, 0, 0);
        }
#pragma unroll
        for (int mtl = 0; mtl < 2; mtl++) {
            const int mt = wave * 2 + mtl;
            const int n0 = mt * 16 + quad * 4;
            f32x4 b4 = *(const f32x4*)(fc1_b + n0);
#pragma unroll
            for (int nt = 0; nt < 4; nt++) {
                float x0 = fmaxf(acc1[mtl][nt][0] + b4[0], 0.f);
                float x1 = fmaxf(acc1[mtl][nt][1] + b4[1], 0.f);
                float x2 = fmaxf(acc1[mtl][nt][2] + b4[2], 0.f);
                float x3 = fmaxf(acc1[mtl][nt][3] + b4[3], 0.f);
                uint2v d;
                d.x = cvt_pk_bf16(x0, x1);
                d.y = cvt_pk_bf16(x2, x3);
                *(uint2v*)(X2 + ((n0 >> 3) * 64 + nt * 16 + mrow) * 8 + (n0 & 7)) = d;
            }
        }
    }
    __syncthreads();  // barrier 2: X2 ready
    const short8* W2v = (const short8*)W2p;
    const short8* W3v = (const short8*)W3p;
    f32x4 acc2[4][4];
#pragma unroll
    for (int a = 0; a < 4; a++)
#pragma unroll
        for (int b = 0; b < 4; b++) acc2[a][b] = (f32x4){0.f, 0.f, 0.f, 0.f};
#pragma unroll
    for (int ks = 0; ks < 4; ks++) {
        short8 bfr[4];
#pragma unroll
        for (int nt = 0; nt < 4; nt++)
            bfr[nt] = *(const short8*)(X2 + ((ks * 4 + quad) * 64 + nt * 16 + mrow) * 8);
#pragma unroll
        for (int q = 0; q < 4; q++) {
            const int mt = q * 4 + wave;
            short8 ah = W2v[(mt * 4 + ks) * 64 + lane];
#pragma unroll
            for (int nt = 0; nt < 4; nt++)
                acc2[q][nt] = __builtin_amdgcn_mfma_f32_16x16x32_bf16(ah, bfr[nt], acc2[q][nt], 0, 0, 0);
        }
    }
    __syncthreads();  // barrier 3: all X2 reads done; X1+X2 regions now dead
#pragma unroll
    for (int q = 0; q < 4; q++) {
        const int mt = q * 4 + wave;
        const int n0 = mt * 16 + quad * 4;  // = k index in [0,256)
        f32x4 b4 = *(const f32x4*)(fc2_b + n0);
#pragma unroll
        for (int nt = 0; nt < 4; nt++) {
            float x0 = fmaxf(acc2[q][nt][0] + b4[0], 0.f);
            float x1 = fmaxf(acc2[q][nt][1] + b4[1], 0.f);
            float x2 = fmaxf(acc2[q][nt][2] + b4[2], 0.f);
            float x3 = fmaxf(acc2[q][nt][3] + b4[3], 0.f);
            uint2v d;
            d.x = cvt_pk_bf16(x0, x1);
            d.y = cvt_pk_bf16(x2, x3);
            *(uint2v*)(X3f + ((n0 >> 3) * 64 + nt * 16 + mrow) * 8 + (n0 & 7)) = d;
        }
    }
    __syncthreads();  // barrier 4: X3full ready
    f32x4 acc3[2][4];
#pragma unroll
    for (int a = 0; a < 2; a++)
#pragma unroll
        for (int b = 0; b < 4; b++) acc3[a][b] = (f32x4){0.f, 0.f, 0.f, 0.f};
#pragma unroll
    for (int ks = 0; ks < 8; ks++) {
        short8 bfr[4];
#pragma unroll
        for (int nt = 0; nt < 4; nt++)
            bfr[nt] = *(const short8*)(X3f + ((ks * 4 + quad) * 64 + nt * 16 + mrow) * 8);
#pragma unroll
        for (int mtl = 0; mtl < 2; mtl++) {
            const int mt = wave * 2 + mtl;
            short8 ah = W3v[(mt * 8 + ks) * 64 + lane];
#pragma unroll
            for (int nt = 0; nt < 4; nt++)
                acc3[mtl][nt] = __builtin_amdgcn_mfma_f32_16x16x32_bf16(ah, bfr[nt], acc3[mtl][nt], 0, 0, 0);
        }
    }
    {
        float p4[4] = {0.f, 0.f, 0.f, 0.f};
#pragma unroll
        for (int mtl = 0; mtl < 2; mtl++) {
            const int mt = wave * 2 + mtl;
            const int n0 = mt * 16 + quad * 4;
            f32x4 b4 = *(const f32x4*)(fc3_b + n0);
            f32x4 w44 = *(const f32x4*)(fc4_w + n0);
#pragma unroll
            for (int nt = 0; nt < 4; nt++)
#pragma unroll
                for (int r = 0; r < 4; r++)
                    p4[nt] = fmaf(fmaxf(acc3[mtl][nt][r] + b4[r], 0.f), w44[r], p4[nt]);
        }
#pragma unroll
        for (int nt = 0; nt < 4; nt++) {
            p4[nt] += __shfl_xor(p4[nt], 16, 64);
            p4[nt] += __shfl_xor(p4[nt], 32, 64);
        }
        if (quad == 0) {
#pragma unroll
            for (int nt = 0; nt < 4; nt++)
                part[wave * 64 + nt * 16 + mrow] = p4[nt];
        }
    }
    __syncthreads();  // barrier 5: part ready
    if (tid < 64) {
        float pred = part[tid] + part[64 + tid] + part[128 + tid] + part[192 + tid] + fc4_b[0];
        preds[p * 256 + e0 + tid] = pred;
    }
}

// ---------------- Kernel 2: propagation only, one WAVE per pair (256 blocks). ----------------
__global__ __launch_bounds__(256)
void prop_kernel(const int* __restrict__ edges, const float* __restrict__ preds,
                 float* __restrict__ rbc_part) {
    const int tid = threadIdx.x;
    const int wave = tid >> 6, lane = tid & 63;
    const int p = blockIdx.x * 4 + wave;
    const int s = p >> 5, t = p & 31;
    __shared__ float xw[4][32], xnw[4][32], raccw[4][32];
    int u[4], v[4];
    float pr[4];
#pragma unroll
    for (int j = 0; j < 4; j++) {
        int e = lane + 64 * j;
        u[j] = edges[2 * e];
        v[j] = edges[2 * e + 1];
        pr[j] = preds[p * 256 + e];
    }
    if (lane < 32) { xw[wave][lane] = (lane == s) ? 1.f : 0.f; raccw[wave][lane] = 0.f; }
    const bool active = (s != t);
    for (int step = 0; step < 3; step++) {
        if (lane < 32) xnw[wave][lane] = 0.f;
        __syncthreads();
        if (active) {
#pragma unroll
            for (int j = 0; j < 4; j++)
                atomicAdd(&xnw[wave][v[j]], xw[wave][u[j]] * pr[j]);
        }
        __syncthreads();
        if (lane < 32) { raccw[wave][lane] += xnw[wave][lane]; xw[wave][lane] = xnw[wave][lane]; }
        __syncthreads();
    }
    if (active && lane < 32) atomicAdd(&rbc_part[(p & 63) * 32 + lane], raccw[wave][lane]);
}

// ---------------- Kernel 3: final reduce + normalize (1 block). ----------------
__global__ __launch_bounds__(256)
void norm_kernel(const float* __restrict__ rbc_part, float* __restrict__ out) {
    const int tid = threadIdx.x;
    const int node = tid & 31, sub = tid >> 5;
    __shared__ float red[8][32];
    float vv = 0.f;
#pragma unroll
    for (int g = 0; g < 8; g++)
        vv += rbc_part[(sub * 8 + g) * 32 + node];
    red[sub][node] = vv;
    __syncthreads();
    if (tid < 32) {
        float acc = 0.f;
#pragma unroll
        for (int sb = 0; sb < 8; sb++) acc += red[sb][tid];
        float tot = acc;
#pragma unroll
        for (int mask = 1; mask < 32; mask <<= 1) tot += __shfl_xor(tot, mask, 32);
        out[tid] = acc / tot;
    }
}

extern "C" void kernel_launch(void* const* d_in, const int* in_sizes, int n_in,
                              void* d_out, int out_size, void* d_ws, size_t ws_size,
                              hipStream_t stream) {
    const float* emb = (const float*)d_in[0];
    const int* edges = (const int*)d_in[1];
    const float* w1 = (const float*)d_in[2];
    const float* b1 = (const float*)d_in[3];
    const float* w2 = (const float*)d_in[4];
    const float* b2 = (const float*)d_in[5];
    const float* w3 = (const float*)d_in[6];
    const float* b3 = (const float*)d_in[7];
    const float* fc1_w = (const float*)d_in[8];
    const float* fc1_b = (const float*)d_in[9];
    const float* fc2_w = (const float*)d_in[10];
    const float* fc2_b = (const float*)d_in[11];
    const float* fc3_w = (const float*)d_in[12];
    const float* fc3_b = (const float*)d_in[13];
    const float* fc4_w = (const float*)d_in[14];
    const float* fc4_b = (const float*)d_in[15];

    float* ws = (float*)d_ws;
    float* G = ws + G_OFF;
    float* H = ws + H_OFF;
    float* preds = ws + PREDS_OFF;
    float* rbc_part = ws + RBCP_OFF;
    unsigned short* W1p = (unsigned short*)(ws + W1P_OFF);
    unsigned short* W2p = (unsigned short*)(ws + W2P_OFF);
    unsigned short* W3p = (unsigned short*)(ws + W3P_OFF);
    float* out = (float*)d_out;

    prep_all<<<dim3(1233), dim3(256), 0, stream>>>(emb, edges, w1, b1, fc1_w, fc2_w, fc3_w,
                                                   G, H, W1p, W2p, W3p, rbc_part);
    mlp_kernel<<<dim3(4096), dim3(256), 0, stream>>>(
        G, H, w2, b2, w3, b3, fc1_b, fc2_b, fc3_b,
        fc4_w, fc4_b, W1p, W2p, W3p, preds);
    prop_kernel<<<dim3(256), dim3(256), 0, stream>>>(edges, preds, rbc_part);
    norm_kernel<<<dim3(1), dim3(256), 0, stream>>>(rbc_part, out);
}

// Round 15
// 148.814 us; speedup vs baseline: 1.1399x; 1.0360x over previous
//
#include <hip/hip_runtime.h>

// ---- ws layout (float offsets) ----
// G: per-pair conv1 tables [1024][4][48] (F_s + F_t)           = 196608 floats
// H: per-edge conv1 tables [256][4][48]  (F_u + F_v + b1)      = 49152 floats
constexpr int G_OFF = 0;
constexpr int H_OFF = 196608;
constexpr int PREDS_OFF = H_OFF + 49152;        // 245760
constexpr int RBCP_OFF = PREDS_OFF + 262144;    // 507904: rbc_part[64][32]
constexpr int CNT_OFF = RBCP_OFF + 2048;        // 509952 (legacy pad)
constexpr int W1P_OFF = CNT_OFF + 16;           // 509968: fc1 A-frags 4096 shorts
constexpr int W2P_OFF = W1P_OFF + 2048;         // 512016: fc2 A-frags 32768 shorts
constexpr int W3P_OFF = W2P_OFF + 16384;        // 528400: fc3 A-frags 32768 shorts

typedef __attribute__((ext_vector_type(8))) short short8;
typedef __attribute__((ext_vector_type(4))) short short4v;
typedef __attribute__((ext_vector_type(4))) float f32x4;
typedef __attribute__((ext_vector_type(2))) unsigned int uint2v;

__device__ __forceinline__ unsigned short f2bf(float x) {  // RNE bf16 (prep only)
    unsigned u = __float_as_uint(x);
    u += 0x7FFF + ((u >> 16) & 1);
    return (unsigned short)(u >> 16);
}

// One-instruction packed f32->bf16 pair (low = a, high = b).
__device__ __forceinline__ unsigned cvt_pk_bf16(float a, float b) {
    unsigned r;
    asm("v_cvt_pk_bf16_f32 %0, %1, %2" : "=v"(r) : "v"(a), "v"(b));
    return r;
}

// quad_perm DPP: lane -> lane^m within each 4-lane quad (VALU, no LDS pipe).
template <int CTRL>
__device__ __forceinline__ float qp(float x) {
    return __int_as_float(__builtin_amdgcn_update_dpp(
        0, __float_as_int(x), CTRL, 0xF, 0xF, true));
}

// ---------------- Kernel 0: all preprocessing ----------------
// b<768: G (pair tables, F_s+F_t). b<960: H (edge tables, F_u+F_v+b1).
// b<976: W1p. b<1104: W2p. b<1232: W3p. b==1232: zero rbc_part.
__global__ void prep_all(const float* __restrict__ emb, const int* __restrict__ edges,
                         const float* __restrict__ w1, const float* __restrict__ b1,
                         const float* __restrict__ fc1_w, const float* __restrict__ fc2_w,
                         const float* __restrict__ fc3_w,
                         float* __restrict__ G, float* __restrict__ H,
                         unsigned short* __restrict__ W1p,
                         unsigned short* __restrict__ W2p, unsigned short* __restrict__ W3p,
                         float* __restrict__ rbcp_zero) {
    int b = blockIdx.x;
    if (b < 768) {  // G[p][o][i] = conv1 contribution of (s as c0) + (t as c1)
        int idx = b * 256 + threadIdx.x;  // 196608
        int i = idx % 48;
        int o = (idx / 48) & 3;
        int p = idx / 192;
        int s = p >> 5, t = p & 31;
        float acc = 0.f;
        if (i < 46) {
#pragma unroll
            for (int k = 0; k < 3; k++)
                acc += w1[(o * 4 + 0) * 3 + k] * emb[s * 96 + 2 * i + k] +
                       w1[(o * 4 + 1) * 3 + k] * emb[t * 96 + 2 * i + k];
        }
        G[idx] = acc;
        return;
    }
    if (b < 960) {  // H[e][o][i] = conv1 contribution of (u as c2) + (v as c3) + b1[o]
        int idx = (b - 768) * 256 + threadIdx.x;  // 49152
        int i = idx % 48;
        int o = (idx / 48) & 3;
        int e = idx / 192;
        int u = edges[2 * e], v = edges[2 * e + 1];
        float acc = 0.f;
        if (i < 46) {
            acc = b1[o];
#pragma unroll
            for (int k = 0; k < 3; k++)
                acc += w1[(o * 4 + 2) * 3 + k] * emb[u * 96 + 2 * i + k] +
                       w1[(o * 4 + 3) * 3 + k] * emb[v * 96 + 2 * i + k];
        }
        H[idx] = acc;
        return;
    }
    if (b < 976) {  // fc1 A-layout, K padded 16->32, single bf16
        int t = (b - 960) * 256 + threadIdx.x;  // 4096
        int j = t & 7, lane = (t >> 3) & 63, mt = t >> 9;
        int k = (lane >> 4) * 8 + j, n = mt * 16 + (lane & 15);
        float w = (k < 16) ? fc1_w[k * 128 + n] : 0.f;
        W1p[t] = f2bf(w);
        return;
    }
    if (b < 1104) {  // fc2 A-layout [16mt][4ks], single bf16
        int t = (b - 976) * 256 + threadIdx.x;  // 32768
        int j = t & 7, lane = (t >> 3) & 63, ks = (t >> 9) & 3, mt = t >> 11;
        int k = ks * 32 + (lane >> 4) * 8 + j, n = mt * 16 + (lane & 15);
        W2p[t] = f2bf(fc2_w[k * 256 + n]);
        return;
    }
    if (b < 1232) {  // fc3 A-layout [8mt][8ks], single bf16
        int t = (b - 1104) * 256 + threadIdx.x;  // 32768
        int j = t & 7, lane = (t >> 3) & 63, ks = (t >> 9) & 7, mt = t >> 12;
        int k = ks * 32 + (lane >> 4) * 8 + j, n = mt * 16 + (lane & 15);
        W3p[t] = f2bf(fc3_w[k * 128 + n]);
        return;
    }
    for (int k = threadIdx.x; k < 2064; k += 256) rbcp_zero[k] = 0.f;  // rbc_part (+legacy)
}

// ---------------- Kernel 1: r10 proven-best monolithic (148.65us total, clean counters:
// FETCH 1765KB / WRITE 992KB / zero spill). G/H split + XCD swizzle + pre[]-array conv
// body + cvt_pk epilogues + 5-barrier X3full.
// Dead ends (do not retry): multi-chunk loop (spills), min-waves>=5 (spill), 64-wide
// sample quarters (flat), fused prop (+19us), one-block-per-pair, DPP-for-shfl (r3:
// neutral), LDS-24K quarters (r4: not LDS-limited; unified VGPR+AGPR~128 caps 16
// waves/CU), batched weight prefetch (r6: compiler re-sinks), counter->extra-kernel
// (r7: ~1us), conv/fc split kernels (r13: C1 HBM round-trip, +17us), "register-lean"
// fused-pool conv body + z8 K-pad (r14: ~3dw/thread scratch spill -> WRITE 13.4MB,
// +9us; judge spill by WRITE_SIZE, NOT VGPR_Count — arch-VGPR pins at 64).
// Phase decomposition (r13): conv ~22us (VALU-issue floor), fc ~43us (MFMA floor ~13
// + epilogue ~14 + stalls). Harness ws-poison fills (~43us x2, 268MB) are fixed
// overhead outside kernel control.
__global__ __launch_bounds__(256, 4)
void mlp_kernel(const float* __restrict__ G, const float* __restrict__ H,
                const float* __restrict__ w2, const float* __restrict__ b2,
                const float* __restrict__ w3, const float* __restrict__ b3,
                const float* __restrict__ fc1_b, const float* __restrict__ fc2_b,
                const float* __restrict__ fc3_b,
                const float* __restrict__ fc4_w, const float* __restrict__ fc4_b,
                const unsigned short* __restrict__ W1p, const unsigned short* __restrict__ W2p,
                const unsigned short* __restrict__ W3p,
                float* __restrict__ preds) {
    // LDS (floats): conv/fc1 phase: X1 at [0,512), X2 at [4096,8192).
    // fc3 phase: X3full spans [0,8192) — overwrites dead X1+X2 after fc2's reads.
    // part at [8192,8448).
    __shared__ __align__(16) float smem[8448];
    unsigned short* X1 = (unsigned short*)smem;
    unsigned short* X3f = (unsigned short*)smem;
    unsigned short* X2 = (unsigned short*)(smem + 4096);
    float* part = smem + 8192;

    const int tid = threadIdx.x;
    // XCD-aware swizzle: xcd = blockIdx.x % 8 owns contiguous work chunk of 512.
    const int bid = (blockIdx.x & 7) * 512 + (blockIdx.x >> 3);
    const int p = bid >> 2;
    const int e0 = (bid & 3) * 64;
    const int s = p >> 5, t = p & 31;
    if (s == t) return;

    const int lane = tid & 63, wave = tid >> 6;
    const int mrow = lane & 15, quad = lane >> 4;

    const int gsample = tid >> 2, o = tid & 3;  // conv roles
    float h1[23];
    // ---- conv1: G[p]+H[e] (bias pre-folded), pool THEN relu -> regs ----
    {
        const int e = e0 + gsample;
        const f32x4* Gp = (const f32x4*)(G + (p * 4 + o) * 48);
        const f32x4* Hp = (const f32x4*)(H + (e * 4 + o) * 48);
        float pre[46];
#pragma unroll
        for (int q = 0; q < 12; q++) {
            f32x4 x = Gp[q] + Hp[q];
#pragma unroll
            for (int z = 0; z < 4; z++) {
                int i = 4 * q + z;
                if (i < 46) pre[i] = x[z];
            }
        }
#pragma unroll
        for (int j = 0; j < 23; j++) h1[j] = fmaxf(fmaxf(pre[2 * j], pre[2 * j + 1]), 0.f);
    }
    float h2[10];
    // ---- conv2: cross-channel via DPP quad_perm, sliding ring; pool+relu fused ----
    {
        float wm[4][3];  // wm[m][k] = w2[o][o^m][k]
#pragma unroll
        for (int m = 0; m < 4; m++)
#pragma unroll
            for (int k = 0; k < 3; k++) wm[m][k] = w2[o * 12 + (o ^ m) * 3 + k];
        const float bb = b2[o];
        float win[4][3];
#pragma unroll
        for (int j = 0; j < 2; j++) {
            float x = h1[j];
            win[0][j] = x;
            win[1][j] = qp<0xB1>(x);
            win[2][j] = qp<0x4E>(x);
            win[3][j] = qp<0x1B>(x);
        }
        float pre[20];
#pragma unroll
        for (int i = 0; i < 20; i++) {
            float x = h1[i + 2];
            win[0][(i + 2) % 3] = x;
            win[1][(i + 2) % 3] = qp<0xB1>(x);
            win[2][(i + 2) % 3] = qp<0x4E>(x);
            win[3][(i + 2) % 3] = qp<0x1B>(x);
            float acc = bb;
#pragma unroll
            for (int m = 0; m < 4; m++)
#pragma unroll
                for (int k = 0; k < 3; k++)
                    acc = fmaf(wm[m][k], win[m][(i + k) % 3], acc);
            pre[i] = acc;
        }
#pragma unroll
        for (int j = 0; j < 10; j++) h2[j] = fmaxf(fmaxf(pre[2 * j], pre[2 * j + 1]), 0.f);
    }
    // ---- conv3; pool+relu fused; cvt_pk pack -> X1 (bf16 B-frag layout, K 16 pad 32) ----
    {
        float wm[4][3];
#pragma unroll
        for (int m = 0; m < 4; m++)
#pragma unroll
            for (int k = 0; k < 3; k++) wm[m][k] = w3[o * 12 + (o ^ m) * 3 + k];
        const float bb = b3[o];
        float win[4][3];
#pragma unroll
        for (int j = 0; j < 2; j++) {
            float x = h2[j];
            win[0][j] = x;
            win[1][j] = qp<0xB1>(x);
            win[2][j] = qp<0x4E>(x);
            win[3][j] = qp<0x1B>(x);
        }
        float pre[8];
#pragma unroll
        for (int i = 0; i < 8; i++) {
            float x = h2[i + 2];
            win[0][(i + 2) % 3] = x;
            win[1][(i + 2) % 3] = qp<0xB1>(x);
            win[2][(i + 2) % 3] = qp<0x4E>(x);
            win[3][(i + 2) % 3] = qp<0x1B>(x);
            float acc = bb;
#pragma unroll
            for (int m = 0; m < 4; m++)
#pragma unroll
                for (int k = 0; k < 3; k++)
                    acc = fmaf(wm[m][k], win[m][(i + k) % 3], acc);
            pre[i] = acc;
        }
        float v0 = fmaxf(fmaxf(pre[0], pre[1]), 0.f);
        float v1 = fmaxf(fmaxf(pre[2], pre[3]), 0.f);
        float v2 = fmaxf(fmaxf(pre[4], pre[5]), 0.f);
        float v3 = fmaxf(fmaxf(pre[6], pre[7]), 0.f);
        uint2v d;
        d.x = cvt_pk_bf16(v0, v1);
        d.y = cvt_pk_bf16(v2, v3);
        *(uint2v*)(X1 + (((o >> 1) * 64 + gsample) * 8) + (o & 1) * 4) = d;
        uint2v z2 = (uint2v){0u, 0u};  // k in [16,32) zeros
        *(uint2v*)(X1 + ((((o >> 1) + 2) * 64 + gsample) * 8) + (o & 1) * 4) = z2;
    }
    const short8* W1v = (const short8*)W1p;
    short8 w1f[2];
#pragma unroll
    for (int mtl = 0; mtl < 2; mtl++)
        w1f[mtl] = W1v[(wave * 2 + mtl) * 64 + lane];
    __syncthreads();  // barrier 1: X1 visible
    // ---- fc1 MFMA: A=w1f, B=X1; epilogue -> X2 ----
    {
        short8 bnt[4];
#pragma unroll
        for (int nt = 0; nt < 4; nt++)
            bnt[nt] = *(const short8*)(X1 + (quad * 64 + nt * 16 + mrow) * 8);
        f32x4 acc1[2][4];
#pragma unroll
        for (int a = 0; a < 2; a++)
#pragma unroll
            for (int b = 0; b < 4; b++) acc1[a][b] = (f32x4){0.f, 0.f, 0.f, 0.f};
#pragma unroll
        for (int mtl = 0; mtl < 2; mtl++) {
#pragma unroll
            for (int nt = 0; nt < 4; nt++)
                acc1[mtl][nt] = __builtin_amdgcn_mfma_f32_16x16x32_bf16(w1f[mtl], bnt[nt], acc1[mtl][nt], 0, 0, 0);
        }
#pragma unroll
        for (int mtl = 0; mtl < 2; mtl++) {
            const int mt = wave * 2 + mtl;
            const int n0 = mt * 16 + quad * 4;
            f32x4 b4 = *(const f32x4*)(fc1_b + n0);
#pragma unroll
            for (int nt = 0; nt < 4; nt++) {
                float x0 = fmaxf(acc1[mtl][nt][0] + b4[0], 0.f);
                float x1 = fmaxf(acc1[mtl][nt][1] + b4[1], 0.f);
                float x2 = fmaxf(acc1[mtl][nt][2] + b4[2], 0.f);
                float x3 = fmaxf(acc1[mtl][nt][3] + b4[3], 0.f);
                uint2v d;
                d.x = cvt_pk_bf16(x0, x1);
                d.y = cvt_pk_bf16(x2, x3);
                *(uint2v*)(X2 + ((n0 >> 3) * 64 + nt * 16 + mrow) * 8 + (n0 & 7)) = d;
            }
        }
    }
    __syncthreads();  // barrier 2: X2 ready
    // ---- fc2: full K=128, wave owns 4 of 16 mt (mt = q*4+wave), acc in regs ----
    const short8* W2v = (const short8*)W2p;
    const short8* W3v = (const short8*)W3p;
    f32x4 acc2[4][4];
#pragma unroll
    for (int a = 0; a < 4; a++)
#pragma unroll
        for (int b = 0; b < 4; b++) acc2[a][b] = (f32x4){0.f, 0.f, 0.f, 0.f};
#pragma unroll
    for (int ks = 0; ks < 4; ks++) {
        short8 bfr[4];
#pragma unroll
        for (int nt = 0; nt < 4; nt++)
            bfr[nt] = *(const short8*)(X2 + ((ks * 4 + quad) * 64 + nt * 16 + mrow) * 8);
#pragma unroll
        for (int q = 0; q < 4; q++) {
            const int mt = q * 4 + wave;
            short8 ah = W2v[(mt * 4 + ks) * 64 + lane];
#pragma unroll
            for (int nt = 0; nt < 4; nt++)
                acc2[q][nt] = __builtin_amdgcn_mfma_f32_16x16x32_bf16(ah, bfr[nt], acc2[q][nt], 0, 0, 0);
        }
    }
    __syncthreads();  // barrier 3: all X2 reads done; X1+X2 regions now dead
    // ---- fc2 epilogue -> X3full (32KB over [0,8192) floats) ----
#pragma unroll
    for (int q = 0; q < 4; q++) {
        const int mt = q * 4 + wave;
        const int n0 = mt * 16 + quad * 4;  // = k index in [0,256)
        f32x4 b4 = *(const f32x4*)(fc2_b + n0);
#pragma unroll
        for (int nt = 0; nt < 4; nt++) {
            float x0 = fmaxf(acc2[q][nt][0] + b4[0], 0.f);
            float x1 = fmaxf(acc2[q][nt][1] + b4[1], 0.f);
            float x2 = fmaxf(acc2[q][nt][2] + b4[2], 0.f);
            float x3 = fmaxf(acc2[q][nt][3] + b4[3], 0.f);
            uint2v d;
            d.x = cvt_pk_bf16(x0, x1);
            d.y = cvt_pk_bf16(x2, x3);
            *(uint2v*)(X3f + ((n0 >> 3) * 64 + nt * 16 + mrow) * 8 + (n0 & 7)) = d;
        }
    }
    __syncthreads();  // barrier 4: X3full ready
    // ---- fc3: all 8 k-steps uninterrupted ----
    f32x4 acc3[2][4];
#pragma unroll
    for (int a = 0; a < 2; a++)
#pragma unroll
        for (int b = 0; b < 4; b++) acc3[a][b] = (f32x4){0.f, 0.f, 0.f, 0.f};
#pragma unroll
    for (int ks = 0; ks < 8; ks++) {
        short8 bfr[4];
#pragma unroll
        for (int nt = 0; nt < 4; nt++)
            bfr[nt] = *(const short8*)(X3f + ((ks * 4 + quad) * 64 + nt * 16 + mrow) * 8);
#pragma unroll
        for (int mtl = 0; mtl < 2; mtl++) {
            const int mt = wave * 2 + mtl;
            short8 ah = W3v[(mt * 8 + ks) * 64 + lane];
#pragma unroll
            for (int nt = 0; nt < 4; nt++)
                acc3[mtl][nt] = __builtin_amdgcn_mfma_f32_16x16x32_bf16(ah, bfr[nt], acc3[mtl][nt], 0, 0, 0);
        }
    }
    // ---- fused fc4 ----
    {
        float p4[4] = {0.f, 0.f, 0.f, 0.f};
#pragma unroll
        for (int mtl = 0; mtl < 2; mtl++) {
            const int mt = wave * 2 + mtl;
            const int n0 = mt * 16 + quad * 4;
            f32x4 b4 = *(const f32x4*)(fc3_b + n0);
            f32x4 w44 = *(const f32x4*)(fc4_w + n0);
#pragma unroll
            for (int nt = 0; nt < 4; nt++)
#pragma unroll
                for (int r = 0; r < 4; r++)
                    p4[nt] = fmaf(fmaxf(acc3[mtl][nt][r] + b4[r], 0.f), w44[r], p4[nt]);
        }
#pragma unroll
        for (int nt = 0; nt < 4; nt++) {
            p4[nt] += __shfl_xor(p4[nt], 16, 64);
            p4[nt] += __shfl_xor(p4[nt], 32, 64);
        }
        if (quad == 0) {
#pragma unroll
            for (int nt = 0; nt < 4; nt++)
                part[wave * 64 + nt * 16 + mrow] = p4[nt];
        }
    }
    __syncthreads();  // barrier 5: part ready
    if (tid < 64) {
        float pred = part[tid] + part[64 + tid] + part[128 + tid] + part[192 + tid] + fc4_b[0];
        preds[p * 256 + e0 + tid] = pred;
    }
}

// ---------------- Kernel 2: propagation only, one WAVE per pair (256 blocks). ----------------
__global__ __launch_bounds__(256)
void prop_kernel(const int* __restrict__ edges, const float* __restrict__ preds,
                 float* __restrict__ rbc_part) {
    const int tid = threadIdx.x;
    const int wave = tid >> 6, lane = tid & 63;
    const int p = blockIdx.x * 4 + wave;
    const int s = p >> 5, t = p & 31;
    __shared__ float xw[4][32], xnw[4][32], raccw[4][32];
    int u[4], v[4];
    float pr[4];
#pragma unroll
    for (int j = 0; j < 4; j++) {
        int e = lane + 64 * j;
        u[j] = edges[2 * e];
        v[j] = edges[2 * e + 1];
        pr[j] = preds[p * 256 + e];
    }
    if (lane < 32) { xw[wave][lane] = (lane == s) ? 1.f : 0.f; raccw[wave][lane] = 0.f; }
    const bool active = (s != t);
    for (int step = 0; step < 3; step++) {
        if (lane < 32) xnw[wave][lane] = 0.f;
        __syncthreads();
        if (active) {
#pragma unroll
            for (int j = 0; j < 4; j++)
                atomicAdd(&xnw[wave][v[j]], xw[wave][u[j]] * pr[j]);
        }
        __syncthreads();
        if (lane < 32) { raccw[wave][lane] += xnw[wave][lane]; xw[wave][lane] = xnw[wave][lane]; }
        __syncthreads();
    }
    if (active && lane < 32) atomicAdd(&rbc_part[(p & 63) * 32 + lane], raccw[wave][lane]);
}

// ---------------- Kernel 3: final reduce + normalize (1 block). ----------------
__global__ __launch_bounds__(256)
void norm_kernel(const float* __restrict__ rbc_part, float* __restrict__ out) {
    const int tid = threadIdx.x;
    const int node = tid & 31, sub = tid >> 5;
    __shared__ float red[8][32];
    float vv = 0.f;
#pragma unroll
    for (int g = 0; g < 8; g++)
        vv += rbc_part[(sub * 8 + g) * 32 + node];
    red[sub][node] = vv;
    __syncthreads();
    if (tid < 32) {
        float acc = 0.f;
#pragma unroll
        for (int sb = 0; sb < 8; sb++) acc += red[sb][tid];
        float tot = acc;
#pragma unroll
        for (int mask = 1; mask < 32; mask <<= 1) tot += __shfl_xor(tot, mask, 32);
        out[tid] = acc / tot;
    }
}

extern "C" void kernel_launch(void* const* d_in, const int* in_sizes, int n_in,
                              void* d_out, int out_size, void* d_ws, size_t ws_size,
                              hipStream_t stream) {
    const float* emb = (const float*)d_in[0];
    const int* edges = (const int*)d_in[1];
    const float* w1 = (const float*)d_in[2];
    const float* b1 = (const float*)d_in[3];
    const float* w2 = (const float*)d_in[4];
    const float* b2 = (const float*)d_in[5];
    const float* w3 = (const float*)d_in[6];
    const float* b3 = (const float*)d_in[7];
    const float* fc1_w = (const float*)d_in[8];
    const float* fc1_b = (const float*)d_in[9];
    const float* fc2_w = (const float*)d_in[10];
    const float* fc2_b = (const float*)d_in[11];
    const float* fc3_w = (const float*)d_in[12];
    const float* fc3_b = (const float*)d_in[13];
    const float* fc4_w = (const float*)d_in[14];
    const float* fc4_b = (const float*)d_in[15];

    float* ws = (float*)d_ws;
    float* G = ws + G_OFF;
    float* H = ws + H_OFF;
    float* preds = ws + PREDS_OFF;
    float* rbc_part = ws + RBCP_OFF;
    unsigned short* W1p = (unsigned short*)(ws + W1P_OFF);
    unsigned short* W2p = (unsigned short*)(ws + W2P_OFF);
    unsigned short* W3p = (unsigned short*)(ws + W3P_OFF);
    float* out = (float*)d_out;

    prep_all<<<dim3(1233), dim3(256), 0, stream>>>(emb, edges, w1, b1, fc1_w, fc2_w, fc3_w,
                                                   G, H, W1p, W2p, W3p, rbc_part);
    mlp_kernel<<<dim3(4096), dim3(256), 0, stream>>>(
        G, H, w2, b2, w3, b3, fc1_b, fc2_b, fc3_b,
        fc4_w, fc4_b, W1p, W2p, W3p, preds);
    prop_kernel<<<dim3(256), dim3(256), 0, stream>>>(edges, preds, rbc_part);
    norm_kernel<<<dim3(1), dim3(256), 0, stream>>>(rbc_part, out);
}

// Round 16
// 148.426 us; speedup vs baseline: 1.1429x; 1.0026x over previous
//
#include <hip/hip_runtime.h>

// ---- ws layout (float offsets) ----
// G: per-pair conv1 tables [1024][4][48] (F_s + F_t)           = 196608 floats
// H: per-edge conv1 tables [256][4][48]  (F_u + F_v + b1)      = 49152 floats
constexpr int G_OFF = 0;
constexpr int H_OFF = 196608;
constexpr int PREDS_OFF = H_OFF + 49152;        // 245760
constexpr int RBCP_OFF = PREDS_OFF + 262144;    // 507904: rbc_part[64][32]
constexpr int CNT_OFF = RBCP_OFF + 2048;        // 509952 (legacy pad)
constexpr int W1P_OFF = CNT_OFF + 16;           // 509968: fc1 A-frags 4096 shorts
constexpr int W2P_OFF = W1P_OFF + 2048;         // 512016: fc2 A-frags 32768 shorts
constexpr int W3P_OFF = W2P_OFF + 16384;        // 528400: fc3 A-frags 32768 shorts

typedef __attribute__((ext_vector_type(8))) short short8;
typedef __attribute__((ext_vector_type(4))) short short4v;
typedef __attribute__((ext_vector_type(4))) float f32x4;
typedef __attribute__((ext_vector_type(2))) unsigned int uint2v;

__device__ __forceinline__ unsigned short f2bf(float x) {  // RNE bf16 (prep only)
    unsigned u = __float_as_uint(x);
    u += 0x7FFF + ((u >> 16) & 1);
    return (unsigned short)(u >> 16);
}

// One-instruction packed f32->bf16 pair (low = a, high = b).
__device__ __forceinline__ unsigned cvt_pk_bf16(float a, float b) {
    unsigned r;
    asm("v_cvt_pk_bf16_f32 %0, %1, %2" : "=v"(r) : "v"(a), "v"(b));
    return r;
}

// quad_perm DPP: lane -> lane^m within each 4-lane quad (VALU, no LDS pipe).
template <int CTRL>
__device__ __forceinline__ float qp(float x) {
    return __int_as_float(__builtin_amdgcn_update_dpp(
        0, __float_as_int(x), CTRL, 0xF, 0xF, true));
}

// ---------------- Kernel 0: all preprocessing ----------------
// b<768: G (pair tables, F_s+F_t). b<960: H (edge tables, F_u+F_v+b1).
// b<976: W1p. b<1104: W2p. b<1232: W3p. b==1232: zero rbc_part.
__global__ void prep_all(const float* __restrict__ emb, const int* __restrict__ edges,
                         const float* __restrict__ w1, const float* __restrict__ b1,
                         const float* __restrict__ fc1_w, const float* __restrict__ fc2_w,
                         const float* __restrict__ fc3_w,
                         float* __restrict__ G, float* __restrict__ H,
                         unsigned short* __restrict__ W1p,
                         unsigned short* __restrict__ W2p, unsigned short* __restrict__ W3p,
                         float* __restrict__ rbcp_zero) {
    int b = blockIdx.x;
    if (b < 768) {  // G[p][o][i] = conv1 contribution of (s as c0) + (t as c1)
        int idx = b * 256 + threadIdx.x;  // 196608
        int i = idx % 48;
        int o = (idx / 48) & 3;
        int p = idx / 192;
        int s = p >> 5, t = p & 31;
        float acc = 0.f;
        if (i < 46) {
#pragma unroll
            for (int k = 0; k < 3; k++)
                acc += w1[(o * 4 + 0) * 3 + k] * emb[s * 96 + 2 * i + k] +
                       w1[(o * 4 + 1) * 3 + k] * emb[t * 96 + 2 * i + k];
        }
        G[idx] = acc;
        return;
    }
    if (b < 960) {  // H[e][o][i] = conv1 contribution of (u as c2) + (v as c3) + b1[o]
        int idx = (b - 768) * 256 + threadIdx.x;  // 49152
        int i = idx % 48;
        int o = (idx / 48) & 3;
        int e = idx / 192;
        int u = edges[2 * e], v = edges[2 * e + 1];
        float acc = 0.f;
        if (i < 46) {
            acc = b1[o];
#pragma unroll
            for (int k = 0; k < 3; k++)
                acc += w1[(o * 4 + 2) * 3 + k] * emb[u * 96 + 2 * i + k] +
                       w1[(o * 4 + 3) * 3 + k] * emb[v * 96 + 2 * i + k];
        }
        H[idx] = acc;
        return;
    }
    if (b < 976) {  // fc1 A-layout, K padded 16->32, single bf16
        int t = (b - 960) * 256 + threadIdx.x;  // 4096
        int j = t & 7, lane = (t >> 3) & 63, mt = t >> 9;
        int k = (lane >> 4) * 8 + j, n = mt * 16 + (lane & 15);
        float w = (k < 16) ? fc1_w[k * 128 + n] : 0.f;
        W1p[t] = f2bf(w);
        return;
    }
    if (b < 1104) {  // fc2 A-layout [16mt][4ks], single bf16
        int t = (b - 976) * 256 + threadIdx.x;  // 32768
        int j = t & 7, lane = (t >> 3) & 63, ks = (t >> 9) & 3, mt = t >> 11;
        int k = ks * 32 + (lane >> 4) * 8 + j, n = mt * 16 + (lane & 15);
        W2p[t] = f2bf(fc2_w[k * 256 + n]);
        return;
    }
    if (b < 1232) {  // fc3 A-layout [8mt][8ks], single bf16
        int t = (b - 1104) * 256 + threadIdx.x;  // 32768
        int j = t & 7, lane = (t >> 3) & 63, ks = (t >> 9) & 7, mt = t >> 12;
        int k = ks * 32 + (lane >> 4) * 8 + j, n = mt * 16 + (lane & 15);
        W3p[t] = f2bf(fc3_w[k * 128 + n]);
        return;
    }
    for (int k = threadIdx.x; k < 2064; k += 256) rbcp_zero[k] = 0.f;  // rbc_part (+legacy)
}

// ---------------- Kernel 1: r10 structure + DENSE grid (3968 blocks, s==t removed).
// Dense pair index pd in [0,992): s = pd/31, r = pd%31, t = r + (r>=s).
// XCD swizzle bijective: 3968 = 8 x 496. preds keeps original p=32s+t indexing
// (prop's active-mask never reads diagonal slots).
// Dead ends (do not retry): multi-chunk loop (spills), min-waves>=5 (spill), 64-wide
// sample quarters (flat), fused prop (+19us), one-block-per-pair, DPP-for-shfl
// (neutral), LDS-24K quarters (not LDS-limited; unified VGPR+AGPR~128 caps 16
// waves/CU — occupancy >16 waves analytically unreachable with acc2[4][4]),
// batched weight prefetch (compiler re-sinks), counter->extra-kernel (~1us),
// conv/fc split kernels (C1 HBM round-trip, +17us), lean fused-pool conv body + z8
// (scratch spill -> WRITE 13.4MB; judge spill by WRITE_SIZE not VGPR_Count).
// Phase floors (r13): conv ~22us VALU-issue, fc ~43us (MFMA ~13 + epilogue + latency).
__global__ __launch_bounds__(256, 4)
void mlp_kernel(const float* __restrict__ G, const float* __restrict__ H,
                const float* __restrict__ w2, const float* __restrict__ b2,
                const float* __restrict__ w3, const float* __restrict__ b3,
                const float* __restrict__ fc1_b, const float* __restrict__ fc2_b,
                const float* __restrict__ fc3_b,
                const float* __restrict__ fc4_w, const float* __restrict__ fc4_b,
                const unsigned short* __restrict__ W1p, const unsigned short* __restrict__ W2p,
                const unsigned short* __restrict__ W3p,
                float* __restrict__ preds) {
    // LDS (floats): conv/fc1 phase: X1 at [0,512), X2 at [4096,8192).
    // fc3 phase: X3full spans [0,8192) — overwrites dead X1+X2 after fc2's reads.
    // part at [8192,8448).
    __shared__ __align__(16) float smem[8448];
    unsigned short* X1 = (unsigned short*)smem;
    unsigned short* X3f = (unsigned short*)smem;
    unsigned short* X2 = (unsigned short*)(smem + 4096);
    float* part = smem + 8192;

    const int tid = threadIdx.x;
    // XCD-aware swizzle over the DENSE grid: each XCD owns 496 contiguous blocks
    // (124 pairs, ~95KB G slice -> L2-resident).
    const int bid = (blockIdx.x & 7) * 496 + (blockIdx.x >> 3);
    const int pd = bid >> 2;            // dense pair index [0,992)
    const int e0 = (bid & 3) * 64;
    const int s = pd / 31;
    const int r = pd - s * 31;
    const int t = r + (r >= s ? 1 : 0);
    const int p = s * 32 + t;           // original pair id for G/preds indexing

    const int lane = tid & 63, wave = tid >> 6;
    const int mrow = lane & 15, quad = lane >> 4;

    const int gsample = tid >> 2, o = tid & 3;  // conv roles
    float h1[23];
    // ---- conv1: G[p]+H[e] (bias pre-folded), pool THEN relu -> regs ----
    {
        const int e = e0 + gsample;
        const f32x4* Gp = (const f32x4*)(G + (p * 4 + o) * 48);
        const f32x4* Hp = (const f32x4*)(H + (e * 4 + o) * 48);
        float pre[46];
#pragma unroll
        for (int q = 0; q < 12; q++) {
            f32x4 x = Gp[q] + Hp[q];
#pragma unroll
            for (int z = 0; z < 4; z++) {
                int i = 4 * q + z;
                if (i < 46) pre[i] = x[z];
            }
        }
#pragma unroll
        for (int j = 0; j < 23; j++) h1[j] = fmaxf(fmaxf(pre[2 * j], pre[2 * j + 1]), 0.f);
    }
    float h2[10];
    // ---- conv2: cross-channel via DPP quad_perm, sliding ring; pool+relu fused ----
    {
        float wm[4][3];  // wm[m][k] = w2[o][o^m][k]
#pragma unroll
        for (int m = 0; m < 4; m++)
#pragma unroll
            for (int k = 0; k < 3; k++) wm[m][k] = w2[o * 12 + (o ^ m) * 3 + k];
        const float bb = b2[o];
        float win[4][3];
#pragma unroll
        for (int j = 0; j < 2; j++) {
            float x = h1[j];
            win[0][j] = x;
            win[1][j] = qp<0xB1>(x);
            win[2][j] = qp<0x4E>(x);
            win[3][j] = qp<0x1B>(x);
        }
        float pre[20];
#pragma unroll
        for (int i = 0; i < 20; i++) {
            float x = h1[i + 2];
            win[0][(i + 2) % 3] = x;
            win[1][(i + 2) % 3] = qp<0xB1>(x);
            win[2][(i + 2) % 3] = qp<0x4E>(x);
            win[3][(i + 2) % 3] = qp<0x1B>(x);
            float acc = bb;
#pragma unroll
            for (int m = 0; m < 4; m++)
#pragma unroll
                for (int k = 0; k < 3; k++)
                    acc = fmaf(wm[m][k], win[m][(i + k) % 3], acc);
            pre[i] = acc;
        }
#pragma unroll
        for (int j = 0; j < 10; j++) h2[j] = fmaxf(fmaxf(pre[2 * j], pre[2 * j + 1]), 0.f);
    }
    // ---- conv3; pool+relu fused; cvt_pk pack -> X1 (bf16 B-frag layout, K 16 pad 32) ----
    {
        float wm[4][3];
#pragma unroll
        for (int m = 0; m < 4; m++)
#pragma unroll
            for (int k = 0; k < 3; k++) wm[m][k] = w3[o * 12 + (o ^ m) * 3 + k];
        const float bb = b3[o];
        float win[4][3];
#pragma unroll
        for (int j = 0; j < 2; j++) {
            float x = h2[j];
            win[0][j] = x;
            win[1][j] = qp<0xB1>(x);
            win[2][j] = qp<0x4E>(x);
            win[3][j] = qp<0x1B>(x);
        }
        float pre[8];
#pragma unroll
        for (int i = 0; i < 8; i++) {
            float x = h2[i + 2];
            win[0][(i + 2) % 3] = x;
            win[1][(i + 2) % 3] = qp<0xB1>(x);
            win[2][(i + 2) % 3] = qp<0x4E>(x);
            win[3][(i + 2) % 3] = qp<0x1B>(x);
            float acc = bb;
#pragma unroll
            for (int m = 0; m < 4; m++)
#pragma unroll
                for (int k = 0; k < 3; k++)
                    acc = fmaf(wm[m][k], win[m][(i + k) % 3], acc);
            pre[i] = acc;
        }
        float v0 = fmaxf(fmaxf(pre[0], pre[1]), 0.f);
        float v1 = fmaxf(fmaxf(pre[2], pre[3]), 0.f);
        float v2 = fmaxf(fmaxf(pre[4], pre[5]), 0.f);
        float v3 = fmaxf(fmaxf(pre[6], pre[7]), 0.f);
        uint2v d;
        d.x = cvt_pk_bf16(v0, v1);
        d.y = cvt_pk_bf16(v2, v3);
        *(uint2v*)(X1 + (((o >> 1) * 64 + gsample) * 8) + (o & 1) * 4) = d;
        uint2v z2 = (uint2v){0u, 0u};  // k in [16,32) zeros
        *(uint2v*)(X1 + ((((o >> 1) + 2) * 64 + gsample) * 8) + (o & 1) * 4) = z2;
    }
    const short8* W1v = (const short8*)W1p;
    short8 w1f[2];
#pragma unroll
    for (int mtl = 0; mtl < 2; mtl++)
        w1f[mtl] = W1v[(wave * 2 + mtl) * 64 + lane];
    __syncthreads();  // barrier 1: X1 visible
    // ---- fc1 MFMA: A=w1f, B=X1; epilogue -> X2 ----
    {
        short8 bnt[4];
#pragma unroll
        for (int nt = 0; nt < 4; nt++)
            bnt[nt] = *(const short8*)(X1 + (quad * 64 + nt * 16 + mrow) * 8);
        f32x4 acc1[2][4];
#pragma unroll
        for (int a = 0; a < 2; a++)
#pragma unroll
            for (int b = 0; b < 4; b++) acc1[a][b] = (f32x4){0.f, 0.f, 0.f, 0.f};
#pragma unroll
        for (int mtl = 0; mtl < 2; mtl++) {
#pragma unroll
            for (int nt = 0; nt < 4; nt++)
                acc1[mtl][nt] = __builtin_amdgcn_mfma_f32_16x16x32_bf16(w1f[mtl], bnt[nt], acc1[mtl][nt], 0, 0, 0);
        }
#pragma unroll
        for (int mtl = 0; mtl < 2; mtl++) {
            const int mt = wave * 2 + mtl;
            const int n0 = mt * 16 + quad * 4;
            f32x4 b4 = *(const f32x4*)(fc1_b + n0);
#pragma unroll
            for (int nt = 0; nt < 4; nt++) {
                float x0 = fmaxf(acc1[mtl][nt][0] + b4[0], 0.f);
                float x1 = fmaxf(acc1[mtl][nt][1] + b4[1], 0.f);
                float x2 = fmaxf(acc1[mtl][nt][2] + b4[2], 0.f);
                float x3 = fmaxf(acc1[mtl][nt][3] + b4[3], 0.f);
                uint2v d;
                d.x = cvt_pk_bf16(x0, x1);
                d.y = cvt_pk_bf16(x2, x3);
                *(uint2v*)(X2 + ((n0 >> 3) * 64 + nt * 16 + mrow) * 8 + (n0 & 7)) = d;
            }
        }
    }
    __syncthreads();  // barrier 2: X2 ready
    // ---- fc2: full K=128, wave owns 4 of 16 mt (mt = q*4+wave), acc in regs ----
    const short8* W2v = (const short8*)W2p;
    const short8* W3v = (const short8*)W3p;
    f32x4 acc2[4][4];
#pragma unroll
    for (int a = 0; a < 4; a++)
#pragma unroll
        for (int b = 0; b < 4; b++) acc2[a][b] = (f32x4){0.f, 0.f, 0.f, 0.f};
#pragma unroll
    for (int ks = 0; ks < 4; ks++) {
        short8 bfr[4];
#pragma unroll
        for (int nt = 0; nt < 4; nt++)
            bfr[nt] = *(const short8*)(X2 + ((ks * 4 + quad) * 64 + nt * 16 + mrow) * 8);
#pragma unroll
        for (int q = 0; q < 4; q++) {
            const int mt = q * 4 + wave;
            short8 ah = W2v[(mt * 4 + ks) * 64 + lane];
#pragma unroll
            for (int nt = 0; nt < 4; nt++)
                acc2[q][nt] = __builtin_amdgcn_mfma_f32_16x16x32_bf16(ah, bfr[nt], acc2[q][nt], 0, 0, 0);
        }
    }
    __syncthreads();  // barrier 3: all X2 reads done; X1+X2 regions now dead
    // ---- fc2 epilogue -> X3full (32KB over [0,8192) floats) ----
#pragma unroll
    for (int q = 0; q < 4; q++) {
        const int mt = q * 4 + wave;
        const int n0 = mt * 16 + quad * 4;  // = k index in [0,256)
        f32x4 b4 = *(const f32x4*)(fc2_b + n0);
#pragma unroll
        for (int nt = 0; nt < 4; nt++) {
            float x0 = fmaxf(acc2[q][nt][0] + b4[0], 0.f);
            float x1 = fmaxf(acc2[q][nt][1] + b4[1], 0.f);
            float x2 = fmaxf(acc2[q][nt][2] + b4[2], 0.f);
            float x3 = fmaxf(acc2[q][nt][3] + b4[3], 0.f);
            uint2v d;
            d.x = cvt_pk_bf16(x0, x1);
            d.y = cvt_pk_bf16(x2, x3);
            *(uint2v*)(X3f + ((n0 >> 3) * 64 + nt * 16 + mrow) * 8 + (n0 & 7)) = d;
        }
    }
    __syncthreads();  // barrier 4: X3full ready
    // ---- fc3: all 8 k-steps uninterrupted ----
    f32x4 acc3[2][4];
#pragma unroll
    for (int a = 0; a < 2; a++)
#pragma unroll
        for (int b = 0; b < 4; b++) acc3[a][b] = (f32x4){0.f, 0.f, 0.f, 0.f};
#pragma unroll
    for (int ks = 0; ks < 8; ks++) {
        short8 bfr[4];
#pragma unroll
        for (int nt = 0; nt < 4; nt++)
            bfr[nt] = *(const short8*)(X3f + ((ks * 4 + quad) * 64 + nt * 16 + mrow) * 8);
#pragma unroll
        for (int mtl = 0; mtl < 2; mtl++) {
            const int mt = wave * 2 + mtl;
            short8 ah = W3v[(mt * 8 + ks) * 64 + lane];
#pragma unroll
            for (int nt = 0; nt < 4; nt++)
                acc3[mtl][nt] = __builtin_amdgcn_mfma_f32_16x16x32_bf16(ah, bfr[nt], acc3[mtl][nt], 0, 0, 0);
        }
    }
    // ---- fused fc4 ----
    {
        float p4[4] = {0.f, 0.f, 0.f, 0.f};
#pragma unroll
        for (int mtl = 0; mtl < 2; mtl++) {
            const int mt = wave * 2 + mtl;
            const int n0 = mt * 16 + quad * 4;
            f32x4 b4 = *(const f32x4*)(fc3_b + n0);
            f32x4 w44 = *(const f32x4*)(fc4_w + n0);
#pragma unroll
            for (int nt = 0; nt < 4; nt++)
#pragma unroll
                for (int r2 = 0; r2 < 4; r2++)
                    p4[nt] = fmaf(fmaxf(acc3[mtl][nt][r2] + b4[r2], 0.f), w44[r2], p4[nt]);
        }
#pragma unroll
        for (int nt = 0; nt < 4; nt++) {
            p4[nt] += __shfl_xor(p4[nt], 16, 64);
            p4[nt] += __shfl_xor(p4[nt], 32, 64);
        }
        if (quad == 0) {
#pragma unroll
            for (int nt = 0; nt < 4; nt++)
                part[wave * 64 + nt * 16 + mrow] = p4[nt];
        }
    }
    __syncthreads();  // barrier 5: part ready
    if (tid < 64) {
        float pred = part[tid] + part[64 + tid] + part[128 + tid] + part[192 + tid] + fc4_b[0];
        preds[p * 256 + e0 + tid] = pred;
    }
}

// ---------------- Kernel 2: propagation only, one WAVE per pair (256 blocks). ----------------
__global__ __launch_bounds__(256)
void prop_kernel(const int* __restrict__ edges, const float* __restrict__ preds,
                 float* __restrict__ rbc_part) {
    const int tid = threadIdx.x;
    const int wave = tid >> 6, lane = tid & 63;
    const int p = blockIdx.x * 4 + wave;
    const int s = p >> 5, t = p & 31;
    __shared__ float xw[4][32], xnw[4][32], raccw[4][32];
    int u[4], v[4];
    float pr[4];
#pragma unroll
    for (int j = 0; j < 4; j++) {
        int e = lane + 64 * j;
        u[j] = edges[2 * e];
        v[j] = edges[2 * e + 1];
        pr[j] = preds[p * 256 + e];
    }
    if (lane < 32) { xw[wave][lane] = (lane == s) ? 1.f : 0.f; raccw[wave][lane] = 0.f; }
    const bool active = (s != t);
    for (int step = 0; step < 3; step++) {
        if (lane < 32) xnw[wave][lane] = 0.f;
        __syncthreads();
        if (active) {
#pragma unroll
            for (int j = 0; j < 4; j++)
                atomicAdd(&xnw[wave][v[j]], xw[wave][u[j]] * pr[j]);
        }
        __syncthreads();
        if (lane < 32) { raccw[wave][lane] += xnw[wave][lane]; xw[wave][lane] = xnw[wave][lane]; }
        __syncthreads();
    }
    if (active && lane < 32) atomicAdd(&rbc_part[(p & 63) * 32 + lane], raccw[wave][lane]);
}

// ---------------- Kernel 3: final reduce + normalize (1 block). ----------------
__global__ __launch_bounds__(256)
void norm_kernel(const float* __restrict__ rbc_part, float* __restrict__ out) {
    const int tid = threadIdx.x;
    const int node = tid & 31, sub = tid >> 5;
    __shared__ float red[8][32];
    float vv = 0.f;
#pragma unroll
    for (int g = 0; g < 8; g++)
        vv += rbc_part[(sub * 8 + g) * 32 + node];
    red[sub][node] = vv;
    __syncthreads();
    if (tid < 32) {
        float acc = 0.f;
#pragma unroll
        for (int sb = 0; sb < 8; sb++) acc += red[sb][tid];
        float tot = acc;
#pragma unroll
        for (int mask = 1; mask < 32; mask <<= 1) tot += __shfl_xor(tot, mask, 32);
        out[tid] = acc / tot;
    }
}

extern "C" void kernel_launch(void* const* d_in, const int* in_sizes, int n_in,
                              void* d_out, int out_size, void* d_ws, size_t ws_size,
                              hipStream_t stream) {
    const float* emb = (const float*)d_in[0];
    const int* edges = (const int*)d_in[1];
    const float* w1 = (const float*)d_in[2];
    const float* b1 = (const float*)d_in[3];
    const float* w2 = (const float*)d_in[4];
    const float* b2 = (const float*)d_in[5];
    const float* w3 = (const float*)d_in[6];
    const float* b3 = (const float*)d_in[7];
    const float* fc1_w = (const float*)d_in[8];
    const float* fc1_b = (const float*)d_in[9];
    const float* fc2_w = (const float*)d_in[10];
    const float* fc2_b = (const float*)d_in[11];
    const float* fc3_w = (const float*)d_in[12];
    const float* fc3_b = (const float*)d_in[13];
    const float* fc4_w = (const float*)d_in[14];
    const float* fc4_b = (const float*)d_in[15];

    float* ws = (float*)d_ws;
    float* G = ws + G_OFF;
    float* H = ws + H_OFF;
    float* preds = ws + PREDS_OFF;
    float* rbc_part = ws + RBCP_OFF;
    unsigned short* W1p = (unsigned short*)(ws + W1P_OFF);
    unsigned short* W2p = (unsigned short*)(ws + W2P_OFF);
    unsigned short* W3p = (unsigned short*)(ws + W3P_OFF);
    float* out = (float*)d_out;

    prep_all<<<dim3(1233), dim3(256), 0, stream>>>(emb, edges, w1, b1, fc1_w, fc2_w, fc3_w,
                                                   G, H, W1p, W2p, W3p, rbc_part);
    mlp_kernel<<<dim3(3968), dim3(256), 0, stream>>>(
        G, H, w2, b2, w3, b3, fc1_b, fc2_b, fc3_b,
        fc4_w, fc4_b, W1p, W2p, W3p, preds);
    prop_kernel<<<dim3(256), dim3(256), 0, stream>>>(edges, preds, rbc_part);
    norm_kernel<<<dim3(1), dim3(256), 0, stream>>>(rbc_part, out);
}